// Round 1
// baseline (894.835 us; speedup 1.0000x reference)
//
#include <hip/hip_runtime.h>
#include <math.h>

#define N_ATOMS 50000
#define IN_DIM 128
#define HID 256
#define N_ELEM 4
#define N_IMG 500
#define NNZ 2000000

__device__ __forceinline__ int elem_of(int z) {
    return (z == 1) ? 0 : (z == 6) ? 1 : (z == 8) ? 2 : 3;
}

// ---------------------------------------------------------------------------
// 1) Bucket atoms by element
// ---------------------------------------------------------------------------
__global__ void bucket_kernel(const int* __restrict__ Z, int* __restrict__ counts,
                              int* __restrict__ lists) {
    int i = blockIdx.x * blockDim.x + threadIdx.x;
    if (i < N_ATOMS) {
        int e = elem_of(Z[i]);
        int pos = atomicAdd(&counts[e], 1);
        lists[e * N_ATOMS + pos] = i;
    }
}

// ---------------------------------------------------------------------------
// 2) Element-wise gathered GEMM: C[atom, n] = act( sum_k A[atom,k] * B[k,n] + bias )
//    TRANSB: B[k][n] = W[n*KD + k]   (W row length == KD)
//    ACT: 0 = none, 1 = tanh, 2 = mulgrad: C = (1 - P^2) * acc  (P read from P buf)
//    Tile: 64(M) x 64(N) x 16(K), 256 threads, 4x4 per thread. fp32.
// ---------------------------------------------------------------------------
template <int KD, int ND, bool TRANSB, int ACT>
__global__ __launch_bounds__(256) void gemm_elem(
    const float* __restrict__ A, int lda,
    const float* __restrict__ W,
    const float* __restrict__ bias,
    float* __restrict__ C, int ldc,
    const float* __restrict__ P,
    const int* __restrict__ counts, const int* __restrict__ lists) {

    const int e = blockIdx.z;
    const int cnt = counts[e];
    const int m0 = blockIdx.x * 64;
    if (m0 >= cnt) return;
    const int n0 = blockIdx.y * 64;
    const int* list = lists + e * N_ATOMS;
    const float* We = W + (size_t)e * KD * ND;

    __shared__ float As[16 * 68];   // As[k][m], stride 68 (16B-aligned, 2-way max)
    __shared__ float Bs[16 * 68];   // Bs[k][n], stride 68

    const int tid = threadIdx.x;
    const int tx = tid & 15;        // n quadrant
    const int ty = tid >> 4;        // m quadrant

    // A-load mapping: one float4 per thread: row mA, k-chunk kcA
    const int mA = tid >> 2;              // 0..63
    const int kcA = (tid & 3) << 2;       // 0,4,8,12
    const int mglob = m0 + mA;
    const float* arow = (mglob < cnt) ? (A + (size_t)list[mglob] * lda) : nullptr;

    float acc[4][4] = {};

    for (int k0 = 0; k0 < KD; k0 += 16) {
        float4 av = make_float4(0.f, 0.f, 0.f, 0.f);
        if (arow) av = *(const float4*)(arow + k0 + kcA);

        if (!TRANSB) {
            const int kB = tid >> 4;              // 0..15
            const int nB4 = (tid & 15) << 2;      // 0..60
            float4 bv = *(const float4*)(We + (size_t)(k0 + kB) * ND + n0 + nB4);
            *(float4*)(&Bs[kB * 68 + nB4]) = bv;
        } else {
            const int nB = tid >> 2;              // 0..63
            const int kcB = (tid & 3) << 2;       // 0,4,8,12
            float4 bv = *(const float4*)(We + (size_t)(n0 + nB) * KD + k0 + kcB);
            Bs[(kcB + 0) * 68 + nB] = bv.x;
            Bs[(kcB + 1) * 68 + nB] = bv.y;
            Bs[(kcB + 2) * 68 + nB] = bv.z;
            Bs[(kcB + 3) * 68 + nB] = bv.w;
        }
        As[(kcA + 0) * 68 + mA] = av.x;
        As[(kcA + 1) * 68 + mA] = av.y;
        As[(kcA + 2) * 68 + mA] = av.z;
        As[(kcA + 3) * 68 + mA] = av.w;
        __syncthreads();

#pragma unroll
        for (int kk = 0; kk < 16; ++kk) {
            float4 a4 = *(const float4*)(&As[kk * 68 + (ty << 2)]);
            float4 b4 = *(const float4*)(&Bs[kk * 68 + (tx << 2)]);
            acc[0][0] += a4.x * b4.x; acc[0][1] += a4.x * b4.y;
            acc[0][2] += a4.x * b4.z; acc[0][3] += a4.x * b4.w;
            acc[1][0] += a4.y * b4.x; acc[1][1] += a4.y * b4.y;
            acc[1][2] += a4.y * b4.z; acc[1][3] += a4.y * b4.w;
            acc[2][0] += a4.z * b4.x; acc[2][1] += a4.z * b4.y;
            acc[2][2] += a4.z * b4.z; acc[2][3] += a4.z * b4.w;
            acc[3][0] += a4.w * b4.x; acc[3][1] += a4.w * b4.y;
            acc[3][2] += a4.w * b4.z; acc[3][3] += a4.w * b4.w;
        }
        __syncthreads();
    }

    // Epilogue
    float bj[4] = {0.f, 0.f, 0.f, 0.f};
    if (ACT == 1) {
        const float* be = bias + e * ND + n0 + (tx << 2);
        bj[0] = be[0]; bj[1] = be[1]; bj[2] = be[2]; bj[3] = be[3];
    }
#pragma unroll
    for (int i = 0; i < 4; ++i) {
        int m = m0 + (ty << 2) + i;
        if (m >= cnt) continue;
        int atom = list[m];
        float* crow = C + (size_t)atom * ldc + n0 + (tx << 2);
        float4 r;
        if (ACT == 1) {
            r.x = tanhf(acc[i][0] + bj[0]);
            r.y = tanhf(acc[i][1] + bj[1]);
            r.z = tanhf(acc[i][2] + bj[2]);
            r.w = tanhf(acc[i][3] + bj[3]);
        } else if (ACT == 2) {
            const float4 p = *(const float4*)(P + (size_t)atom * ldc + n0 + (tx << 2));
            r.x = acc[i][0] * (1.f - p.x * p.x);
            r.y = acc[i][1] * (1.f - p.y * p.y);
            r.z = acc[i][2] * (1.f - p.z * p.z);
            r.w = acc[i][3] * (1.f - p.w * p.w);
        } else {
            r.x = acc[i][0]; r.y = acc[i][1]; r.z = acc[i][2]; r.w = acc[i][3];
        }
        *(float4*)crow = r;
    }
}

// ---------------------------------------------------------------------------
// 3) Per-atom output + dz1: o = H1 . W2[e] + b2[e]; energy[img] += o;
//    DZ1[h] = W2[e][h] * (1 - h1^2)   (in-place over H1)
// ---------------------------------------------------------------------------
__global__ __launch_bounds__(256) void out_dz1_kernel(
    const float* __restrict__ H1, const float* __restrict__ W2,
    const float* __restrict__ b2, const int* __restrict__ Z,
    const int* __restrict__ img, float* __restrict__ energy,
    float* __restrict__ DZ1) {
    const int atom = blockIdx.x;
    const int h = threadIdx.x;
    const int e = elem_of(Z[atom]);
    const float h1 = H1[(size_t)atom * HID + h];
    const float w = W2[e * HID + h];
    float p = h1 * w;
    DZ1[(size_t)atom * HID + h] = w * (1.f - h1 * h1);

    // reduce p over the block (4 waves of 64)
    __shared__ float red[4];
    for (int off = 32; off > 0; off >>= 1) p += __shfl_down(p, off, 64);
    if ((h & 63) == 0) red[h >> 6] = p;
    __syncthreads();
    if (h == 0) {
        float o = red[0] + red[1] + red[2] + red[3] + b2[e];
        atomicAdd(&energy[img[atom]], o);
    }
}

// ---------------------------------------------------------------------------
// 4) Forces: F[col] -= val * g[row]  over the COO triplets
// ---------------------------------------------------------------------------
__global__ __launch_bounds__(256) void forces_kernel(
    const int* __restrict__ rows, const int* __restrict__ cols,
    const float* __restrict__ vals, const float* __restrict__ g,
    float* __restrict__ F) {
    int i = blockIdx.x * blockDim.x + threadIdx.x;
    const int stride = gridDim.x * blockDim.x;
    for (; i < NNZ; i += stride) {
        atomicAdd(&F[cols[i]], -vals[i] * g[rows[i]]);
    }
}

// ---------------------------------------------------------------------------
extern "C" void kernel_launch(void* const* d_in, const int* in_sizes, int n_in,
                              void* d_out, int out_size, void* d_ws, size_t ws_size,
                              hipStream_t stream) {
    const float* fp    = (const float*)d_in[0];
    const int*   Z     = (const int*)d_in[1];
    const int*   img   = (const int*)d_in[2];
    const int*   frows = (const int*)d_in[3];
    const int*   fcols = (const int*)d_in[4];
    const float* fvals = (const float*)d_in[5];
    const float* W0    = (const float*)d_in[6];
    const float* b0    = (const float*)d_in[7];
    const float* W1    = (const float*)d_in[8];
    const float* b1    = (const float*)d_in[9];
    const float* W2    = (const float*)d_in[10];
    const float* b2    = (const float*)d_in[11];

    float* out    = (float*)d_out;
    float* energy = out;             // [N_IMG]
    float* F      = out + N_IMG;     // [3*N_ATOMS]

    char* ws = (char*)d_ws;
    int*   counts = (int*)ws;                                  // 4 ints
    int*   lists  = (int*)(ws + 256);                          // 4 * N_ATOMS ints
    float* H0 = (float*)(ws + (1 << 20));                      // 50000*256 f32
    float* H1 = (float*)(ws + (1 << 20) + 51200000);           // 50000*256 f32
    float* G  = (float*)(ws + (1 << 20) + 102400000);          // 50000*128 f32

    hipMemsetAsync(d_out, 0, (size_t)(N_IMG + 3 * N_ATOMS) * sizeof(float), stream);
    hipMemsetAsync(counts, 0, 4 * sizeof(int), stream);

    bucket_kernel<<<(N_ATOMS + 255) / 256, 256, 0, stream>>>(Z, counts, lists);

    const int MT = (N_ATOMS + 63) / 64;   // 782 m-tiles (early-exit past count[e])
    dim3 g256(MT, 4, N_ELEM);
    dim3 g128(MT, 2, N_ELEM);

    // fwd: H0 = tanh(fp @ W0 + b0);  H1 = tanh(H0 @ W1 + b1)
    gemm_elem<128, 256, false, 1><<<g256, 256, 0, stream>>>(fp, 128, W0, b0, H0, 256, nullptr, counts, lists);
    gemm_elem<256, 256, false, 1><<<g256, 256, 0, stream>>>(H0, 256, W1, b1, H1, 256, nullptr, counts, lists);

    // o + energy + dz1 (in-place over H1)
    out_dz1_kernel<<<N_ATOMS, 256, 0, stream>>>(H1, W2, b2, Z, img, energy, H1);

    // dh0 = dz1 @ W1^T ; dz0 = (1-h0^2)*dh0  (in-place over H0)
    gemm_elem<256, 256, true, 2><<<g256, 256, 0, stream>>>(H1, 256, W1, nullptr, H0, 256, H0, counts, lists);
    // g = dz0 @ W0^T
    gemm_elem<256, 128, true, 0><<<g128, 256, 0, stream>>>(H0, 256, W0, nullptr, G, 128, nullptr, counts, lists);

    // forces scatter
    forces_kernel<<<1024, 256, 0, stream>>>(frows, fcols, fvals, G, F);
}

// Round 2
// 671.941 us; speedup vs baseline: 1.3317x; 1.3317x over previous
//
#include <hip/hip_runtime.h>
#include <math.h>

#define N_ATOMS 50000
#define IN_DIM 128
#define HID 256
#define N_ELEM 4
#define N_IMG 500
#define NNZ 2000000

__device__ __forceinline__ int elem_of(int z) {
    return (z == 1) ? 0 : (z == 6) ? 1 : (z == 8) ? 2 : 3;
}

// ---------------------------------------------------------------------------
// 1) Bucket atoms by element — wave-aggregated atomics.
//    R0 post-mortem: 50k scalar atomicAdds on 4 addresses serialized at L2
//    (~271 us, 30% of total). One ballot + one atomic per wave per element
//    cuts global atomics ~16x and makes each a single wave-wide op.
// ---------------------------------------------------------------------------
__global__ __launch_bounds__(256) void bucket_kernel(
    const int* __restrict__ Z, int* __restrict__ counts, int* __restrict__ lists) {
    const int i = blockIdx.x * blockDim.x + threadIdx.x;
    const int e = (i < N_ATOMS) ? elem_of(Z[i]) : -1;
    const int lane = threadIdx.x & 63;
    const unsigned long long lt = (1ull << lane) - 1ull;
#pragma unroll
    for (int el = 0; el < N_ELEM; ++el) {
        unsigned long long m = __ballot(e == el);
        if (e == el) {
            int rank = __popcll(m & lt);
            int base = 0;
            if (rank == 0) base = atomicAdd(&counts[el], __popcll(m));
            int first = __ffsll((long long)m) - 1;
            base = __shfl(base, first, 64);
            lists[el * N_ATOMS + base + rank] = i;
        }
    }
}

// ---------------------------------------------------------------------------
// 2) Element-wise gathered GEMM: C[atom, n] = act( sum_k A[atom,k] * B[k,n] + bias )
//    TRANSB: B[k][n] = W[n*KD + k]   (W row length == KD)
//    ACT: 0 = none, 1 = tanh, 2 = mulgrad: C = (1 - P^2) * acc  (P read from P buf)
//    Tile: 64(M) x 64(N) x 16(K), 256 threads, 4x4 per thread. fp32.
// ---------------------------------------------------------------------------
template <int KD, int ND, bool TRANSB, int ACT>
__global__ __launch_bounds__(256) void gemm_elem(
    const float* __restrict__ A, int lda,
    const float* __restrict__ W,
    const float* __restrict__ bias,
    float* __restrict__ C, int ldc,
    const float* __restrict__ P,
    const int* __restrict__ counts, const int* __restrict__ lists) {

    const int e = blockIdx.z;
    const int cnt = counts[e];
    const int m0 = blockIdx.x * 64;
    if (m0 >= cnt) return;
    const int n0 = blockIdx.y * 64;
    const int* list = lists + e * N_ATOMS;
    const float* We = W + (size_t)e * KD * ND;

    __shared__ float As[16 * 68];   // As[k][m], stride 68 (16B-aligned, 2-way max)
    __shared__ float Bs[16 * 68];   // Bs[k][n], stride 68

    const int tid = threadIdx.x;
    const int tx = tid & 15;        // n quadrant
    const int ty = tid >> 4;        // m quadrant

    // A-load mapping: one float4 per thread: row mA, k-chunk kcA
    const int mA = tid >> 2;              // 0..63
    const int kcA = (tid & 3) << 2;       // 0,4,8,12
    const int mglob = m0 + mA;
    const float* arow = (mglob < cnt) ? (A + (size_t)list[mglob] * lda) : nullptr;

    float acc[4][4] = {};

    for (int k0 = 0; k0 < KD; k0 += 16) {
        float4 av = make_float4(0.f, 0.f, 0.f, 0.f);
        if (arow) av = *(const float4*)(arow + k0 + kcA);

        if (!TRANSB) {
            const int kB = tid >> 4;              // 0..15
            const int nB4 = (tid & 15) << 2;      // 0..60
            float4 bv = *(const float4*)(We + (size_t)(k0 + kB) * ND + n0 + nB4);
            *(float4*)(&Bs[kB * 68 + nB4]) = bv;
        } else {
            const int nB = tid >> 2;              // 0..63
            const int kcB = (tid & 3) << 2;       // 0,4,8,12
            float4 bv = *(const float4*)(We + (size_t)(n0 + nB) * KD + k0 + kcB);
            Bs[(kcB + 0) * 68 + nB] = bv.x;
            Bs[(kcB + 1) * 68 + nB] = bv.y;
            Bs[(kcB + 2) * 68 + nB] = bv.z;
            Bs[(kcB + 3) * 68 + nB] = bv.w;
        }
        As[(kcA + 0) * 68 + mA] = av.x;
        As[(kcA + 1) * 68 + mA] = av.y;
        As[(kcA + 2) * 68 + mA] = av.z;
        As[(kcA + 3) * 68 + mA] = av.w;
        __syncthreads();

#pragma unroll
        for (int kk = 0; kk < 16; ++kk) {
            float4 a4 = *(const float4*)(&As[kk * 68 + (ty << 2)]);
            float4 b4 = *(const float4*)(&Bs[kk * 68 + (tx << 2)]);
            acc[0][0] += a4.x * b4.x; acc[0][1] += a4.x * b4.y;
            acc[0][2] += a4.x * b4.z; acc[0][3] += a4.x * b4.w;
            acc[1][0] += a4.y * b4.x; acc[1][1] += a4.y * b4.y;
            acc[1][2] += a4.y * b4.z; acc[1][3] += a4.y * b4.w;
            acc[2][0] += a4.z * b4.x; acc[2][1] += a4.z * b4.y;
            acc[2][2] += a4.z * b4.z; acc[2][3] += a4.z * b4.w;
            acc[3][0] += a4.w * b4.x; acc[3][1] += a4.w * b4.y;
            acc[3][2] += a4.w * b4.z; acc[3][3] += a4.w * b4.w;
        }
        __syncthreads();
    }

    // Epilogue
    float bj[4] = {0.f, 0.f, 0.f, 0.f};
    if (ACT == 1) {
        const float* be = bias + e * ND + n0 + (tx << 2);
        bj[0] = be[0]; bj[1] = be[1]; bj[2] = be[2]; bj[3] = be[3];
    }
#pragma unroll
    for (int i = 0; i < 4; ++i) {
        int m = m0 + (ty << 2) + i;
        if (m >= cnt) continue;
        int atom = list[m];
        float* crow = C + (size_t)atom * ldc + n0 + (tx << 2);
        float4 r;
        if (ACT == 1) {
            r.x = tanhf(acc[i][0] + bj[0]);
            r.y = tanhf(acc[i][1] + bj[1]);
            r.z = tanhf(acc[i][2] + bj[2]);
            r.w = tanhf(acc[i][3] + bj[3]);
        } else if (ACT == 2) {
            const float4 p = *(const float4*)(P + (size_t)atom * ldc + n0 + (tx << 2));
            r.x = acc[i][0] * (1.f - p.x * p.x);
            r.y = acc[i][1] * (1.f - p.y * p.y);
            r.z = acc[i][2] * (1.f - p.z * p.z);
            r.w = acc[i][3] * (1.f - p.w * p.w);
        } else {
            r.x = acc[i][0]; r.y = acc[i][1]; r.z = acc[i][2]; r.w = acc[i][3];
        }
        *(float4*)crow = r;
    }
}

// ---------------------------------------------------------------------------
// 3) Per-atom output + dz1: o = H1 . W2[e] + b2[e]; energy[img] += o;
//    DZ1[h] = W2[e][h] * (1 - h1^2)   (in-place over H1)
// ---------------------------------------------------------------------------
__global__ __launch_bounds__(256) void out_dz1_kernel(
    const float* __restrict__ H1, const float* __restrict__ W2,
    const float* __restrict__ b2, const int* __restrict__ Z,
    const int* __restrict__ img, float* __restrict__ energy,
    float* __restrict__ DZ1) {
    const int atom = blockIdx.x;
    const int h = threadIdx.x;
    const int e = elem_of(Z[atom]);
    const float h1 = H1[(size_t)atom * HID + h];
    const float w = W2[e * HID + h];
    float p = h1 * w;
    DZ1[(size_t)atom * HID + h] = w * (1.f - h1 * h1);

    // reduce p over the block (4 waves of 64)
    __shared__ float red[4];
    for (int off = 32; off > 0; off >>= 1) p += __shfl_down(p, off, 64);
    if ((h & 63) == 0) red[h >> 6] = p;
    __syncthreads();
    if (h == 0) {
        float o = red[0] + red[1] + red[2] + red[3] + b2[e];
        atomicAdd(&energy[img[atom]], o);
    }
}

// ---------------------------------------------------------------------------
// 4) Forces: F[col] -= val * g[row]  over the COO triplets
// ---------------------------------------------------------------------------
__global__ __launch_bounds__(256) void forces_kernel(
    const int* __restrict__ rows, const int* __restrict__ cols,
    const float* __restrict__ vals, const float* __restrict__ g,
    float* __restrict__ F) {
    int i = blockIdx.x * blockDim.x + threadIdx.x;
    const int stride = gridDim.x * blockDim.x;
    for (; i < NNZ; i += stride) {
        atomicAdd(&F[cols[i]], -vals[i] * g[rows[i]]);
    }
}

// ---------------------------------------------------------------------------
extern "C" void kernel_launch(void* const* d_in, const int* in_sizes, int n_in,
                              void* d_out, int out_size, void* d_ws, size_t ws_size,
                              hipStream_t stream) {
    const float* fp    = (const float*)d_in[0];
    const int*   Z     = (const int*)d_in[1];
    const int*   img   = (const int*)d_in[2];
    const int*   frows = (const int*)d_in[3];
    const int*   fcols = (const int*)d_in[4];
    const float* fvals = (const float*)d_in[5];
    const float* W0    = (const float*)d_in[6];
    const float* b0    = (const float*)d_in[7];
    const float* W1    = (const float*)d_in[8];
    const float* b1    = (const float*)d_in[9];
    const float* W2    = (const float*)d_in[10];
    const float* b2    = (const float*)d_in[11];

    float* out    = (float*)d_out;
    float* energy = out;             // [N_IMG]
    float* F      = out + N_IMG;     // [3*N_ATOMS]

    char* ws = (char*)d_ws;
    int*   counts = (int*)ws;                                  // 4 ints
    int*   lists  = (int*)(ws + 256);                          // 4 * N_ATOMS ints
    float* H0 = (float*)(ws + (1 << 20));                      // 50000*256 f32
    float* H1 = (float*)(ws + (1 << 20) + 51200000);           // 50000*256 f32
    float* G  = (float*)(ws + (1 << 20) + 102400000);          // 50000*128 f32

    hipMemsetAsync(d_out, 0, (size_t)(N_IMG + 3 * N_ATOMS) * sizeof(float), stream);
    hipMemsetAsync(counts, 0, 4 * sizeof(int), stream);

    bucket_kernel<<<(N_ATOMS + 255) / 256, 256, 0, stream>>>(Z, counts, lists);

    const int MT = (N_ATOMS + 63) / 64;   // 782 m-tiles (early-exit past count[e])
    dim3 g256(MT, 4, N_ELEM);
    dim3 g128(MT, 2, N_ELEM);

    // fwd: H0 = tanh(fp @ W0 + b0);  H1 = tanh(H0 @ W1 + b1)
    gemm_elem<128, 256, false, 1><<<g256, 256, 0, stream>>>(fp, 128, W0, b0, H0, 256, nullptr, counts, lists);
    gemm_elem<256, 256, false, 1><<<g256, 256, 0, stream>>>(H0, 256, W1, b1, H1, 256, nullptr, counts, lists);

    // o + energy + dz1 (in-place over H1)
    out_dz1_kernel<<<N_ATOMS, 256, 0, stream>>>(H1, W2, b2, Z, img, energy, H1);

    // dh0 = dz1 @ W1^T ; dz0 = (1-h0^2)*dh0  (in-place over H0)
    gemm_elem<256, 256, true, 2><<<g256, 256, 0, stream>>>(H1, 256, W1, nullptr, H0, 256, H0, counts, lists);
    // g = dz0 @ W0^T
    gemm_elem<256, 128, true, 0><<<g128, 256, 0, stream>>>(H0, 256, W0, nullptr, G, 128, nullptr, counts, lists);

    // forces scatter
    forces_kernel<<<1024, 256, 0, stream>>>(frows, fcols, fvals, G, F);
}

// Round 3
// 587.710 us; speedup vs baseline: 1.5226x; 1.1433x over previous
//
#include <hip/hip_runtime.h>
#include <math.h>

#define N_ATOMS 50000
#define IN_DIM 128
#define HID 256
#define N_ELEM 4
#define N_IMG 500
#define NNZ 2000000

__device__ __forceinline__ int elem_of(int z) {
    return (z == 1) ? 0 : (z == 6) ? 1 : (z == 8) ? 2 : 3;
}

// ---------------------------------------------------------------------------
// 1) Bucket atoms by element — wave-aggregated atomics (R1: 271us -> ~10us).
// ---------------------------------------------------------------------------
__global__ __launch_bounds__(256) void bucket_kernel(
    const int* __restrict__ Z, int* __restrict__ counts, int* __restrict__ lists) {
    const int i = blockIdx.x * blockDim.x + threadIdx.x;
    const int e = (i < N_ATOMS) ? elem_of(Z[i]) : -1;
    const int lane = threadIdx.x & 63;
    const unsigned long long lt = (1ull << lane) - 1ull;
#pragma unroll
    for (int el = 0; el < N_ELEM; ++el) {
        unsigned long long m = __ballot(e == el);
        if (e == el) {
            int rank = __popcll(m & lt);
            int base = 0;
            if (rank == 0) base = atomicAdd(&counts[el], __popcll(m));
            int first = __ffsll((long long)m) - 1;
            base = __shfl(base, first, 64);
            lists[el * N_ATOMS + base + rank] = i;
        }
    }
}

// ---------------------------------------------------------------------------
// 2) Element-wise gathered GEMM (fp32, 64x64x16 tile, 4x4/thread).
// ---------------------------------------------------------------------------
template <int KD, int ND, bool TRANSB, int ACT>
__global__ __launch_bounds__(256) void gemm_elem(
    const float* __restrict__ A, int lda,
    const float* __restrict__ W,
    const float* __restrict__ bias,
    float* __restrict__ C, int ldc,
    const float* __restrict__ P,
    const int* __restrict__ counts, const int* __restrict__ lists) {

    const int e = blockIdx.z;
    const int cnt = counts[e];
    const int m0 = blockIdx.x * 64;
    if (m0 >= cnt) return;
    const int n0 = blockIdx.y * 64;
    const int* list = lists + e * N_ATOMS;
    const float* We = W + (size_t)e * KD * ND;

    __shared__ float As[16 * 68];   // As[k][m]
    __shared__ float Bs[16 * 68];   // Bs[k][n]

    const int tid = threadIdx.x;
    const int tx = tid & 15;
    const int ty = tid >> 4;

    const int mA = tid >> 2;
    const int kcA = (tid & 3) << 2;
    const int mglob = m0 + mA;
    const float* arow = (mglob < cnt) ? (A + (size_t)list[mglob] * lda) : nullptr;

    float acc[4][4] = {};

    for (int k0 = 0; k0 < KD; k0 += 16) {
        float4 av = make_float4(0.f, 0.f, 0.f, 0.f);
        if (arow) av = *(const float4*)(arow + k0 + kcA);

        if (!TRANSB) {
            const int kB = tid >> 4;
            const int nB4 = (tid & 15) << 2;
            float4 bv = *(const float4*)(We + (size_t)(k0 + kB) * ND + n0 + nB4);
            *(float4*)(&Bs[kB * 68 + nB4]) = bv;
        } else {
            const int nB = tid >> 2;
            const int kcB = (tid & 3) << 2;
            float4 bv = *(const float4*)(We + (size_t)(n0 + nB) * KD + k0 + kcB);
            Bs[(kcB + 0) * 68 + nB] = bv.x;
            Bs[(kcB + 1) * 68 + nB] = bv.y;
            Bs[(kcB + 2) * 68 + nB] = bv.z;
            Bs[(kcB + 3) * 68 + nB] = bv.w;
        }
        As[(kcA + 0) * 68 + mA] = av.x;
        As[(kcA + 1) * 68 + mA] = av.y;
        As[(kcA + 2) * 68 + mA] = av.z;
        As[(kcA + 3) * 68 + mA] = av.w;
        __syncthreads();

#pragma unroll
        for (int kk = 0; kk < 16; ++kk) {
            float4 a4 = *(const float4*)(&As[kk * 68 + (ty << 2)]);
            float4 b4 = *(const float4*)(&Bs[kk * 68 + (tx << 2)]);
            acc[0][0] += a4.x * b4.x; acc[0][1] += a4.x * b4.y;
            acc[0][2] += a4.x * b4.z; acc[0][3] += a4.x * b4.w;
            acc[1][0] += a4.y * b4.x; acc[1][1] += a4.y * b4.y;
            acc[1][2] += a4.y * b4.z; acc[1][3] += a4.y * b4.w;
            acc[2][0] += a4.z * b4.x; acc[2][1] += a4.z * b4.y;
            acc[2][2] += a4.z * b4.z; acc[2][3] += a4.z * b4.w;
            acc[3][0] += a4.w * b4.x; acc[3][1] += a4.w * b4.y;
            acc[3][2] += a4.w * b4.z; acc[3][3] += a4.w * b4.w;
        }
        __syncthreads();
    }

    float bj[4] = {0.f, 0.f, 0.f, 0.f};
    if (ACT == 1) {
        const float* be = bias + e * ND + n0 + (tx << 2);
        bj[0] = be[0]; bj[1] = be[1]; bj[2] = be[2]; bj[3] = be[3];
    }
#pragma unroll
    for (int i = 0; i < 4; ++i) {
        int m = m0 + (ty << 2) + i;
        if (m >= cnt) continue;
        int atom = list[m];
        float* crow = C + (size_t)atom * ldc + n0 + (tx << 2);
        float4 r;
        if (ACT == 1) {
            r.x = tanhf(acc[i][0] + bj[0]);
            r.y = tanhf(acc[i][1] + bj[1]);
            r.z = tanhf(acc[i][2] + bj[2]);
            r.w = tanhf(acc[i][3] + bj[3]);
        } else if (ACT == 2) {
            const float4 p = *(const float4*)(P + (size_t)atom * ldc + n0 + (tx << 2));
            r.x = acc[i][0] * (1.f - p.x * p.x);
            r.y = acc[i][1] * (1.f - p.y * p.y);
            r.z = acc[i][2] * (1.f - p.z * p.z);
            r.w = acc[i][3] * (1.f - p.w * p.w);
        } else {
            r.x = acc[i][0]; r.y = acc[i][1]; r.z = acc[i][2]; r.w = acc[i][3];
        }
        *(float4*)crow = r;
    }
}

// ---------------------------------------------------------------------------
// 3) Per-atom output + dz1 — R2 restructure. One WAVE per atom per iteration
//    (grid-stride), lane l owns a float4 slice of HID. No energy atomics:
//    o[atom] goes to scratch; energy is reduced per-image in energy_kernel.
//    R1 post-mortem: 50k tiny blocks + 50k atomics on 500 sorted addresses
//    serialized (140us for 81MB of traffic). This version is pure streaming.
// ---------------------------------------------------------------------------
__global__ __launch_bounds__(256) void out_dz1_kernel(
    const float* __restrict__ H1, const float* __restrict__ W2,
    const float* __restrict__ b2, const int* __restrict__ Z,
    float* __restrict__ o_atom, float* __restrict__ DZ1) {
    const int gtid = blockIdx.x * blockDim.x + threadIdx.x;
    const int wave = gtid >> 6;
    const int lane = threadIdx.x & 63;
    const int nwaves = (gridDim.x * blockDim.x) >> 6;
    for (int atom = wave; atom < N_ATOMS; atom += nwaves) {
        const int e = elem_of(Z[atom]);
        const float4 h1 = *(const float4*)(H1 + (size_t)atom * HID + (lane << 2));
        const float4 w  = *(const float4*)(W2 + e * HID + (lane << 2));
        float p = h1.x * w.x + h1.y * w.y + h1.z * w.z + h1.w * w.w;
        float4 dz;
        dz.x = w.x * (1.f - h1.x * h1.x);
        dz.y = w.y * (1.f - h1.y * h1.y);
        dz.z = w.z * (1.f - h1.z * h1.z);
        dz.w = w.w * (1.f - h1.w * h1.w);
        *(float4*)(DZ1 + (size_t)atom * HID + (lane << 2)) = dz;
#pragma unroll
        for (int off = 32; off > 0; off >>= 1) p += __shfl_down(p, off, 64);
        if (lane == 0) o_atom[atom] = p + b2[e];
    }
}

// ---------------------------------------------------------------------------
// 3b) Energy: one block per image; img is SORTED, so each image is a
//     contiguous range — binary search bounds, block-reduce, direct store.
// ---------------------------------------------------------------------------
__global__ __launch_bounds__(256) void energy_kernel(
    const float* __restrict__ o_atom, const int* __restrict__ img,
    float* __restrict__ energy) {
    const int b = blockIdx.x;
    int lo, hi;
    {
        int l = 0, r = N_ATOMS;
        while (l < r) { int m = (l + r) >> 1; if (img[m] < b) l = m + 1; else r = m; }
        lo = l;
    }
    {
        int l = lo, r = N_ATOMS;
        while (l < r) { int m = (l + r) >> 1; if (img[m] < b + 1) l = m + 1; else r = m; }
        hi = l;
    }
    float s = 0.f;
    for (int i = lo + (int)threadIdx.x; i < hi; i += (int)blockDim.x) s += o_atom[i];
#pragma unroll
    for (int off = 32; off > 0; off >>= 1) s += __shfl_down(s, off, 64);
    __shared__ float red[4];
    if ((threadIdx.x & 63) == 0) red[threadIdx.x >> 6] = s;
    __syncthreads();
    if (threadIdx.x == 0) energy[b] = red[0] + red[1] + red[2] + red[3];
}

// ---------------------------------------------------------------------------
// 4) Forces: F[col] -= val * g[row]  over the COO triplets
// ---------------------------------------------------------------------------
__global__ __launch_bounds__(256) void forces_kernel(
    const int* __restrict__ rows, const int* __restrict__ cols,
    const float* __restrict__ vals, const float* __restrict__ g,
    float* __restrict__ F) {
    int i = blockIdx.x * blockDim.x + threadIdx.x;
    const int stride = gridDim.x * blockDim.x;
    for (; i < NNZ; i += stride) {
        atomicAdd(&F[cols[i]], -vals[i] * g[rows[i]]);
    }
}

// ---------------------------------------------------------------------------
extern "C" void kernel_launch(void* const* d_in, const int* in_sizes, int n_in,
                              void* d_out, int out_size, void* d_ws, size_t ws_size,
                              hipStream_t stream) {
    const float* fp    = (const float*)d_in[0];
    const int*   Z     = (const int*)d_in[1];
    const int*   img   = (const int*)d_in[2];
    const int*   frows = (const int*)d_in[3];
    const int*   fcols = (const int*)d_in[4];
    const float* fvals = (const float*)d_in[5];
    const float* W0    = (const float*)d_in[6];
    const float* b0    = (const float*)d_in[7];
    const float* W1    = (const float*)d_in[8];
    const float* b1    = (const float*)d_in[9];
    const float* W2    = (const float*)d_in[10];
    const float* b2    = (const float*)d_in[11];

    float* out    = (float*)d_out;
    float* energy = out;             // [N_IMG]
    float* F      = out + N_IMG;     // [3*N_ATOMS]

    char* ws = (char*)d_ws;
    int*   counts = (int*)ws;                                  // 4 ints
    int*   lists  = (int*)(ws + 256);                          // 4 * N_ATOMS ints
    float* H0     = (float*)(ws + (1 << 20));                  // 50000*256 f32
    float* H1     = (float*)(ws + (1 << 20) + 51200000);       // 50000*256 f32
    float* G      = (float*)(ws + (1 << 20) + 102400000);      // 50000*128 f32
    float* o_atom = (float*)(ws + (1 << 20) + 128000000);      // 50000 f32

    hipMemsetAsync(d_out, 0, (size_t)(N_IMG + 3 * N_ATOMS) * sizeof(float), stream);
    hipMemsetAsync(counts, 0, 4 * sizeof(int), stream);

    bucket_kernel<<<(N_ATOMS + 255) / 256, 256, 0, stream>>>(Z, counts, lists);

    const int MT = (N_ATOMS + 63) / 64;
    dim3 g256(MT, 4, N_ELEM);
    dim3 g128(MT, 2, N_ELEM);

    // fwd: H0 = tanh(fp @ W0 + b0);  H1 = tanh(H0 @ W1 + b1)
    gemm_elem<128, 256, false, 1><<<g256, 256, 0, stream>>>(fp, 128, W0, b0, H0, 256, nullptr, counts, lists);
    gemm_elem<256, 256, false, 1><<<g256, 256, 0, stream>>>(H0, 256, W1, b1, H1, 256, nullptr, counts, lists);

    // o + dz1 (in-place over H1), then per-image energy (no atomics)
    out_dz1_kernel<<<1024, 256, 0, stream>>>(H1, W2, b2, Z, o_atom, H1);
    energy_kernel<<<N_IMG, 256, 0, stream>>>(o_atom, img, energy);

    // dh0 = dz1 @ W1^T ; dz0 = (1-h0^2)*dh0  (in-place over H0)
    gemm_elem<256, 256, true, 2><<<g256, 256, 0, stream>>>(H1, 256, W1, nullptr, H0, 256, H0, counts, lists);
    // g = dz0 @ W0^T
    gemm_elem<256, 128, true, 0><<<g128, 256, 0, stream>>>(H0, 256, W0, nullptr, G, 128, nullptr, counts, lists);

    // forces scatter
    forces_kernel<<<1024, 256, 0, stream>>>(frows, fcols, fvals, G, F);
}

// Round 4
// 423.685 us; speedup vs baseline: 2.1120x; 1.3871x over previous
//
#include <hip/hip_runtime.h>
#include <math.h>

#define N_ATOMS 50000
#define IN_DIM 128
#define HID 256
#define N_ELEM 4
#define N_IMG 500
#define NNZ 2000000

typedef __attribute__((ext_vector_type(8))) short bf16x8;   // 8 bf16 = 4 VGPRs
typedef __attribute__((ext_vector_type(4))) float f32x4;    // MFMA C/D frag

__device__ __forceinline__ int elem_of(int z) {
    return (z == 1) ? 0 : (z == 6) ? 1 : (z == 8) ? 2 : 3;
}

// fp32 -> bf16 round-to-nearest-even
__device__ __forceinline__ unsigned short f2bf(float f) {
    unsigned u = __float_as_uint(f);
    u += 0x7fffu + ((u >> 16) & 1u);
    return (unsigned short)(u >> 16);
}

// tanh via v_exp_f32 (~1e-5 abs err, far below bf16 GEMM noise; stable both tails)
__device__ __forceinline__ float tanh_fast(float x) {
    float e = __expf(2.f * x);
    return (e - 1.f) / (e + 1.f);
}

// ---------------------------------------------------------------------------
// 1) Bucket atoms by element — wave-aggregated atomics (R1: 271us -> ~10us).
// ---------------------------------------------------------------------------
__global__ __launch_bounds__(256) void bucket_kernel(
    const int* __restrict__ Z, int* __restrict__ counts, int* __restrict__ lists) {
    const int i = blockIdx.x * blockDim.x + threadIdx.x;
    const int e = (i < N_ATOMS) ? elem_of(Z[i]) : -1;
    const int lane = threadIdx.x & 63;
    const unsigned long long lt = (1ull << lane) - 1ull;
#pragma unroll
    for (int el = 0; el < N_ELEM; ++el) {
        unsigned long long m = __ballot(e == el);
        if (e == el) {
            int rank = __popcll(m & lt);
            int base = 0;
            if (rank == 0) base = atomicAdd(&counts[el], __popcll(m));
            int first = __ffsll((long long)m) - 1;
            base = __shfl(base, first, 64);
            lists[el * N_ATOMS + base + rank] = i;
        }
    }
}

// ---------------------------------------------------------------------------
// 1b) Weight prep: bf16 plain copies (used as B^T for the backward GEMMs —
//     W row-major IS B^T row-major there) + bf16 transposed copies (forward).
// ---------------------------------------------------------------------------
__global__ __launch_bounds__(256) void prep_weights(
    const float* __restrict__ W0, const float* __restrict__ W1,
    unsigned short* __restrict__ W0b, unsigned short* __restrict__ W0T,
    unsigned short* __restrict__ W1b, unsigned short* __restrict__ W1T) {
    int t = blockIdx.x * 256 + threadIdx.x;
    if (t >= N_ELEM * HID * HID) return;
    int e = t >> 16;          // 256*256 per element
    int rem = t & 65535;
    int k = rem >> 8, n = rem & 255;
    unsigned short w1 = f2bf(W1[t]);
    W1b[t] = w1;                                    // [e][k][n]
    W1T[(e << 16) + (n << 8) + k] = w1;             // [e][n][k]
    if (k < IN_DIM) {
        int i0 = e * (IN_DIM * HID) + rem;          // rem = k*256+n, k<128
        unsigned short w0 = f2bf(W0[i0]);
        W0b[i0] = w0;                               // [e][k][n]
        W0T[e * (IN_DIM * HID) + n * IN_DIM + k] = w0;  // [e][n][k]
    }
}

// ---------------------------------------------------------------------------
// 2) Gathered MFMA GEMM, bf16 inputs / fp32 accumulate.
//    C[m][n] = act( sum_k A[m][k]*B[k][n] + bias ), rows gathered via lists.
//    A fp32 in memory, converted to bf16 during LDS staging. Bt = B^T
//    row-major [ND][KD] bf16 so B-frag k runs are contiguous.
//    Block 256 thr = 4 waves (2x2), tile 128(M)x128(N), BK=32.
//    mfma_f32_16x16x32_bf16; A/B frag: [m|n = lane&15][k = (lane>>4)*8+j];
//    C/D: col = lane&15, row = (lane>>4)*4 + reg  (guide §3, m89-verified).
//    LDS rows padded to 40 shorts (80 B = 20 banks -> 2-way = free, m136).
//    ACT: 0 none, 1 tanh+bias, 2 val *= (1 - P^2) (P read at same coords).
// ---------------------------------------------------------------------------
template <int KD, int ND, int ACT>
__global__ __launch_bounds__(256, 2) void mfma_gemm(
    const float* __restrict__ A,
    const unsigned short* __restrict__ Bt,
    const float* __restrict__ bias,
    float* __restrict__ C,
    const float* __restrict__ P,
    const int* __restrict__ counts, const int* __restrict__ lists) {

    const int e = blockIdx.z;
    const int cnt = counts[e];
    const int m0 = blockIdx.x * 128;
    if (m0 >= cnt) return;
    const int n0 = blockIdx.y * 128;
    const int* list = lists + e * N_ATOMS;
    const unsigned short* Be = Bt + (size_t)e * KD * ND;

    __shared__ short As[128 * 40];
    __shared__ short Bs[128 * 40];

    const int tid = threadIdx.x;
    const int lane = tid & 63;
    const int wave = tid >> 6;
    const int wm = wave & 1, wn = wave >> 1;
    const int lr = lane & 15;
    const int lq = lane >> 4;

    f32x4 acc[4][4];
#pragma unroll
    for (int mt = 0; mt < 4; ++mt)
#pragma unroll
        for (int nt = 0; nt < 4; ++nt)
#pragma unroll
            for (int j = 0; j < 4; ++j) acc[mt][nt][j] = 0.f;

    for (int k0 = 0; k0 < KD; k0 += 32) {
        // ---- stage A (fp32 -> bf16): 2 chunks/thread; c = tid + 256t,
        //      row = c&127, kslot = c>>7 -> consecutive lanes hit consecutive
        //      rows (write stride 80 B -> 2-way bank alias, free).
#pragma unroll
        for (int t = 0; t < 2; ++t) {
            int c = tid + 256 * t;
            int row = c & 127, ks = c >> 7;
            bf16x8 v;
#pragma unroll
            for (int j = 0; j < 8; ++j) v[j] = 0;
            int m = m0 + row;
            if (m < cnt) {
                const float* src = A + (size_t)list[m] * KD + k0 + ks * 8;
                float4 a0 = *(const float4*)src;
                float4 a1 = *(const float4*)(src + 4);
                v[0] = (short)f2bf(a0.x); v[1] = (short)f2bf(a0.y);
                v[2] = (short)f2bf(a0.z); v[3] = (short)f2bf(a0.w);
                v[4] = (short)f2bf(a1.x); v[5] = (short)f2bf(a1.y);
                v[6] = (short)f2bf(a1.z); v[7] = (short)f2bf(a1.w);
            }
            *(bf16x8*)&As[row * 40 + ks * 8] = v;
        }
        // ---- stage B (already bf16): 2 chunks/thread
#pragma unroll
        for (int t = 0; t < 2; ++t) {
            int c = tid + 256 * t;
            int row = c & 127, ks = c >> 7;
            bf16x8 v = *(const bf16x8*)(Be + (size_t)(n0 + row) * KD + k0 + ks * 8);
            *(bf16x8*)&Bs[row * 40 + ks * 8] = v;
        }
        __syncthreads();

        bf16x8 af[4], bfr[4];
#pragma unroll
        for (int mt = 0; mt < 4; ++mt)
            af[mt] = *(const bf16x8*)&As[(wm * 64 + mt * 16 + lr) * 40 + lq * 8];
#pragma unroll
        for (int nt = 0; nt < 4; ++nt)
            bfr[nt] = *(const bf16x8*)&Bs[(wn * 64 + nt * 16 + lr) * 40 + lq * 8];
#pragma unroll
        for (int mt = 0; mt < 4; ++mt)
#pragma unroll
            for (int nt = 0; nt < 4; ++nt)
                acc[mt][nt] = __builtin_amdgcn_mfma_f32_16x16x32_bf16(
                    af[mt], bfr[nt], acc[mt][nt], 0, 0, 0);
        __syncthreads();
    }

    // ---- epilogue
    float bv[4];
    if (ACT == 1) {
#pragma unroll
        for (int nt = 0; nt < 4; ++nt)
            bv[nt] = bias[e * ND + n0 + wn * 64 + nt * 16 + lr];
    }
#pragma unroll
    for (int mt = 0; mt < 4; ++mt) {
#pragma unroll
        for (int r = 0; r < 4; ++r) {
            int m = m0 + wm * 64 + mt * 16 + lq * 4 + r;
            if (m >= cnt) continue;
            int atom = list[m];
#pragma unroll
            for (int nt = 0; nt < 4; ++nt) {
                int n = n0 + wn * 64 + nt * 16 + lr;
                float val = acc[mt][nt][r];
                if (ACT == 1) {
                    val = tanh_fast(val + bv[nt]);
                } else if (ACT == 2) {
                    float p = P[(size_t)atom * ND + n];
                    val *= (1.f - p * p);
                }
                C[(size_t)atom * ND + n] = val;
            }
        }
    }
}

// ---------------------------------------------------------------------------
// 3) Per-atom output + dz1 — one wave/atom, no atomics (R2: 143us -> ~15us).
// ---------------------------------------------------------------------------
__global__ __launch_bounds__(256) void out_dz1_kernel(
    const float* __restrict__ H1, const float* __restrict__ W2,
    const float* __restrict__ b2, const int* __restrict__ Z,
    float* __restrict__ o_atom, float* __restrict__ DZ1) {
    const int gtid = blockIdx.x * blockDim.x + threadIdx.x;
    const int wave = gtid >> 6;
    const int lane = threadIdx.x & 63;
    const int nwaves = (gridDim.x * blockDim.x) >> 6;
    for (int atom = wave; atom < N_ATOMS; atom += nwaves) {
        const int e = elem_of(Z[atom]);
        const float4 h1 = *(const float4*)(H1 + (size_t)atom * HID + (lane << 2));
        const float4 w  = *(const float4*)(W2 + e * HID + (lane << 2));
        float p = h1.x * w.x + h1.y * w.y + h1.z * w.z + h1.w * w.w;
        float4 dz;
        dz.x = w.x * (1.f - h1.x * h1.x);
        dz.y = w.y * (1.f - h1.y * h1.y);
        dz.z = w.z * (1.f - h1.z * h1.z);
        dz.w = w.w * (1.f - h1.w * h1.w);
        *(float4*)(DZ1 + (size_t)atom * HID + (lane << 2)) = dz;
#pragma unroll
        for (int off = 32; off > 0; off >>= 1) p += __shfl_down(p, off, 64);
        if (lane == 0) o_atom[atom] = p + b2[e];
    }
}

// ---------------------------------------------------------------------------
// 3b) Energy: one block/image; img sorted -> contiguous range; no atomics.
// ---------------------------------------------------------------------------
__global__ __launch_bounds__(256) void energy_kernel(
    const float* __restrict__ o_atom, const int* __restrict__ img,
    float* __restrict__ energy) {
    const int b = blockIdx.x;
    int lo, hi;
    {
        int l = 0, r = N_ATOMS;
        while (l < r) { int m = (l + r) >> 1; if (img[m] < b) l = m + 1; else r = m; }
        lo = l;
    }
    {
        int l = lo, r = N_ATOMS;
        while (l < r) { int m = (l + r) >> 1; if (img[m] < b + 1) l = m + 1; else r = m; }
        hi = l;
    }
    float s = 0.f;
    for (int i = lo + (int)threadIdx.x; i < hi; i += (int)blockDim.x) s += o_atom[i];
#pragma unroll
    for (int off = 32; off > 0; off >>= 1) s += __shfl_down(s, off, 64);
    __shared__ float red[4];
    if ((threadIdx.x & 63) == 0) red[threadIdx.x >> 6] = s;
    __syncthreads();
    if (threadIdx.x == 0) energy[b] = red[0] + red[1] + red[2] + red[3];
}

// ---------------------------------------------------------------------------
// 4) Forces — R3 post-mortem: latency-bound (21% BW, 7.6 sequential dependent
//    gathers/thread). Now: 4 elems/thread via int4/float4 loads -> 4
//    independent gathers in flight, single pass, max occupancy.
// ---------------------------------------------------------------------------
__global__ __launch_bounds__(256) void forces_kernel(
    const int* __restrict__ rows, const int* __restrict__ cols,
    const float* __restrict__ vals, const float* __restrict__ g,
    float* __restrict__ F) {
    const int i4 = (blockIdx.x * 256 + threadIdx.x) * 4;
    if (i4 >= NNZ) return;
    int4 r = *(const int4*)(rows + i4);
    int4 c = *(const int4*)(cols + i4);
    float4 v = *(const float4*)(vals + i4);
    float g0 = g[r.x], g1 = g[r.y], g2 = g[r.z], g3 = g[r.w];
    atomicAdd(&F[c.x], -v.x * g0);
    atomicAdd(&F[c.y], -v.y * g1);
    atomicAdd(&F[c.z], -v.z * g2);
    atomicAdd(&F[c.w], -v.w * g3);
}

// ---------------------------------------------------------------------------
extern "C" void kernel_launch(void* const* d_in, const int* in_sizes, int n_in,
                              void* d_out, int out_size, void* d_ws, size_t ws_size,
                              hipStream_t stream) {
    const float* fp    = (const float*)d_in[0];
    const int*   Z     = (const int*)d_in[1];
    const int*   img   = (const int*)d_in[2];
    const int*   frows = (const int*)d_in[3];
    const int*   fcols = (const int*)d_in[4];
    const float* fvals = (const float*)d_in[5];
    const float* W0    = (const float*)d_in[6];
    const float* b0    = (const float*)d_in[7];
    const float* W1    = (const float*)d_in[8];
    const float* b1    = (const float*)d_in[9];
    const float* W2    = (const float*)d_in[10];
    const float* b2    = (const float*)d_in[11];

    float* out    = (float*)d_out;
    float* energy = out;             // [N_IMG]
    float* F      = out + N_IMG;     // [3*N_ATOMS]

    char* ws = (char*)d_ws;
    int*   counts = (int*)ws;                                   // 16 B
    int*   lists  = (int*)(ws + 1024);                          // 800 KB
    float* H0     = (float*)(ws + (1 << 20));                   // 50000*256 f32 (later: dz0)
    float* H1     = (float*)(ws + (1 << 20) + 51200000);        // 50000*256 f32 (later: dz1)
    float* G      = (float*)(ws + (1 << 20) + 102400000);       // 50000*128 f32
    float* o_atom = (float*)(ws + (1 << 20) + 128000000);       // 50000 f32
    unsigned short* W0b = (unsigned short*)(ws + (1 << 20) + 128400000); // 4*128*256 bf16
    unsigned short* W0T = W0b + N_ELEM * IN_DIM * HID;                    // [e][n][k]
    unsigned short* W1b = W0T + N_ELEM * IN_DIM * HID;                    // 4*256*256 bf16
    unsigned short* W1T = W1b + N_ELEM * HID * HID;                       // [e][n][k]

    hipMemsetAsync(d_out, 0, (size_t)(N_IMG + 3 * N_ATOMS) * sizeof(float), stream);
    hipMemsetAsync(counts, 0, 4 * sizeof(int), stream);

    bucket_kernel<<<(N_ATOMS + 255) / 256, 256, 0, stream>>>(Z, counts, lists);
    prep_weights<<<(N_ELEM * HID * HID + 255) / 256, 256, 0, stream>>>(
        W0, W1, W0b, W0T, W1b, W1T);

    const int MT = (N_ATOMS + 127) / 128;   // 391

    // fwd: H0 = tanh(fp @ W0 + b0)          B^T = W0T [n][k]
    mfma_gemm<128, 256, 1><<<dim3(MT, 2, N_ELEM), 256, 0, stream>>>(
        fp, W0T, b0, H0, nullptr, counts, lists);
    // fwd: H1 = tanh(H0 @ W1 + b1)          B^T = W1T [n][k]
    mfma_gemm<256, 256, 1><<<dim3(MT, 2, N_ELEM), 256, 0, stream>>>(
        H0, W1T, b1, H1, nullptr, counts, lists);

    // o + dz1 (in-place over H1), per-image energy
    out_dz1_kernel<<<1024, 256, 0, stream>>>(H1, W2, b2, Z, o_atom, H1);
    energy_kernel<<<N_IMG, 256, 0, stream>>>(o_atom, img, energy);

    // bwd: dz0 = (1-H0^2) * (dz1 @ W1^T)    B = W1^T -> B^T row-major = W1 plain
    //      (P=H0 read & C=H0 write at same coords by same thread: safe in-place)
    mfma_gemm<256, 256, 2><<<dim3(MT, 2, N_ELEM), 256, 0, stream>>>(
        H1, W1b, nullptr, H0, H0, counts, lists);
    // bwd: g = dz0 @ W0^T                   B = W0^T -> B^T row-major = W0 plain
    mfma_gemm<256, 128, 0><<<dim3(MT, 1, N_ELEM), 256, 0, stream>>>(
        H0, W0b, nullptr, G, nullptr, counts, lists);

    // forces scatter
    forces_kernel<<<(NNZ / 4 + 255) / 256, 256, 0, stream>>>(frows, fcols, fvals, G, F);
}

// Round 5
// 366.815 us; speedup vs baseline: 2.4395x; 1.1550x over previous
//
#include <hip/hip_runtime.h>
#include <math.h>

#define N_ATOMS 50000
#define IN_DIM 128
#define HID 256
#define N_ELEM 4
#define N_IMG 500
#define NNZ 2000000

typedef __attribute__((ext_vector_type(8))) short bf16x8;   // 8 bf16 = 4 VGPRs
typedef __attribute__((ext_vector_type(4))) float f32x4;    // MFMA C/D frag

__device__ __forceinline__ int elem_of(int z) {
    return (z == 1) ? 0 : (z == 6) ? 1 : (z == 8) ? 2 : 3;
}

// fp32 -> bf16 round-to-nearest-even
__device__ __forceinline__ unsigned short f2bf(float f) {
    unsigned u = __float_as_uint(f);
    u += 0x7fffu + ((u >> 16) & 1u);
    return (unsigned short)(u >> 16);
}

__device__ __forceinline__ float tanh_fast(float x) {
    float e = __expf(2.f * x);
    return (e - 1.f) / (e + 1.f);
}

// ---------------------------------------------------------------------------
// 1) Bucket atoms by element — LDS-aggregated (R4 post-mortem: wave-aggregated
//    still did ~3.1k serialized global atomics on 4 addrs; now 4/block).
// ---------------------------------------------------------------------------
__global__ __launch_bounds__(256) void bucket_kernel(
    const int* __restrict__ Z, int* __restrict__ counts, int* __restrict__ lists) {
    __shared__ int lcnt[N_ELEM], lbase[N_ELEM];
    const int i = blockIdx.x * blockDim.x + threadIdx.x;
    if (threadIdx.x < N_ELEM) lcnt[threadIdx.x] = 0;
    __syncthreads();
    int e = -1, pos = 0;
    if (i < N_ATOMS) {
        e = elem_of(Z[i]);
        pos = atomicAdd(&lcnt[e], 1);
    }
    __syncthreads();
    if (threadIdx.x < N_ELEM)
        lbase[threadIdx.x] = atomicAdd(&counts[threadIdx.x], lcnt[threadIdx.x]);
    __syncthreads();
    if (i < N_ATOMS) lists[e * N_ATOMS + lbase[e] + pos] = i;
}

// ---------------------------------------------------------------------------
// 1b) Weight prep: bf16 plain ([e][k][n], used as B^T in backward) and
//     transposed ([e][n][k], used as B^T in forward).
// ---------------------------------------------------------------------------
__global__ __launch_bounds__(256) void prep_weights(
    const float* __restrict__ W0, const float* __restrict__ W1,
    unsigned short* __restrict__ W0b, unsigned short* __restrict__ W0T,
    unsigned short* __restrict__ W1b, unsigned short* __restrict__ W1T) {
    int t = blockIdx.x * 256 + threadIdx.x;
    if (t >= N_ELEM * HID * HID) return;
    int e = t >> 16;
    int rem = t & 65535;
    int k = rem >> 8, n = rem & 255;
    unsigned short w1 = f2bf(W1[t]);
    W1b[t] = w1;
    W1T[(e << 16) + (n << 8) + k] = w1;
    if (k < IN_DIM) {
        int i0 = e * (IN_DIM * HID) + rem;
        unsigned short w0 = f2bf(W0[i0]);
        W0b[i0] = w0;
        W0T[e * (IN_DIM * HID) + n * IN_DIM + k] = w0;
    }
}

// ---------------------------------------------------------------------------
// 2) Gathered MFMA GEMM, bf16/fp32-acc. Tile 128(M) x BN(N), BN == ND (full N
//    per block -> A fetched once per GEMM; R4 post-mortem: 2 n-tiles doubled
//    the gathered fp32 A traffic, ~130 MB excess across the 4 GEMMs).
//    4 waves as 2(m) x 2(n); per wave 64 x BN/2; NT = BN/32 MFMA cols.
//    mfma_f32_16x16x32_bf16; A/B frag [row=lane&15][k=(lane>>4)*8+j];
//    C/D col=lane&15, row=(lane>>4)*4+reg (m89-verified).
//    LDS rows 40 shorts (80 B -> 2-way alias, free per m136).
//    ACT: 0 none; 1 tanh(acc+bias); 2 acc*(1-P^2);
//         3 fused: t=tanh(acc+bias); C=W2[n]*(1-t^2) (dz1); o=sum_n t*W2[n]
//           cross-lane+LDS reduced, o_atom[atom]=o+b2[e]. H1 never hits HBM.
// ---------------------------------------------------------------------------
template <int KD, int ND, int BN, int ACT>
__global__ __launch_bounds__(256, 2) void mfma_gemm(
    const float* __restrict__ A,
    const unsigned short* __restrict__ Bt,
    const float* __restrict__ bias,
    float* __restrict__ C,
    const float* __restrict__ P,
    const float* __restrict__ W2,
    const float* __restrict__ b2,
    float* __restrict__ o_atom,
    const int* __restrict__ counts, const int* __restrict__ lists) {

    constexpr int NT = BN / 32;            // MFMA col-tiles per wave
    const int e = blockIdx.z;
    const int cnt = counts[e];
    const int m0 = blockIdx.x * 128;
    if (m0 >= cnt) return;
    const int* list = lists + e * N_ATOMS;
    const unsigned short* Be = Bt + (size_t)e * KD * ND;

    __shared__ short As[128 * 40];
    __shared__ short Bs[BN * 40];
    __shared__ float red[2][128];

    const int tid = threadIdx.x;
    const int lane = tid & 63;
    const int wave = tid >> 6;
    const int wm = wave & 1, wn = wave >> 1;
    const int lr = lane & 15;
    const int lq = lane >> 4;

    // Hoisted A-row pointers for this thread's 2 staging chunks
    const float* arow[2];
#pragma unroll
    for (int t = 0; t < 2; ++t) {
        int c = tid + 256 * t;
        int row = c & 127;
        int m = m0 + row;
        arow[t] = (m < cnt) ? (A + (size_t)list[m] * KD) : nullptr;
    }

    f32x4 acc[4][NT];
#pragma unroll
    for (int mt = 0; mt < 4; ++mt)
#pragma unroll
        for (int nt = 0; nt < NT; ++nt)
#pragma unroll
            for (int j = 0; j < 4; ++j) acc[mt][nt][j] = 0.f;

    for (int k0 = 0; k0 < KD; k0 += 32) {
        // ---- stage A (fp32 -> bf16): 512 chunks of 8, 2/thread
#pragma unroll
        for (int t = 0; t < 2; ++t) {
            int c = tid + 256 * t;
            int row = c & 127, ks = c >> 7;          // ks in 0..3
            bf16x8 v;
#pragma unroll
            for (int j = 0; j < 8; ++j) v[j] = 0;
            if (arow[t]) {
                const float* src = arow[t] + k0 + ks * 8;
                float4 a0 = *(const float4*)src;
                float4 a1 = *(const float4*)(src + 4);
                v[0] = (short)f2bf(a0.x); v[1] = (short)f2bf(a0.y);
                v[2] = (short)f2bf(a0.z); v[3] = (short)f2bf(a0.w);
                v[4] = (short)f2bf(a1.x); v[5] = (short)f2bf(a1.y);
                v[6] = (short)f2bf(a1.z); v[7] = (short)f2bf(a1.w);
            }
            *(bf16x8*)&As[row * 40 + ks * 8] = v;
        }
        // ---- stage B (bf16): BN*4 chunks, BN/64 per thread
#pragma unroll
        for (int t = 0; t < BN / 64; ++t) {
            int c = tid + 256 * t;
            int row = c & (BN - 1), ks = c / BN;     // ks in 0..3
            bf16x8 v = *(const bf16x8*)(Be + (size_t)row * KD + k0 + ks * 8);
            *(bf16x8*)&Bs[row * 40 + ks * 8] = v;
        }
        __syncthreads();

        bf16x8 af[4], bfr[NT];
#pragma unroll
        for (int mt = 0; mt < 4; ++mt)
            af[mt] = *(const bf16x8*)&As[(wm * 64 + mt * 16 + lr) * 40 + lq * 8];
#pragma unroll
        for (int nt = 0; nt < NT; ++nt)
            bfr[nt] = *(const bf16x8*)&Bs[(wn * (BN / 2) + nt * 16 + lr) * 40 + lq * 8];
#pragma unroll
        for (int mt = 0; mt < 4; ++mt)
#pragma unroll
            for (int nt = 0; nt < NT; ++nt)
                acc[mt][nt] = __builtin_amdgcn_mfma_f32_16x16x32_bf16(
                    af[mt], bfr[nt], acc[mt][nt], 0, 0, 0);
        __syncthreads();
    }

    // ---- epilogue
    float bv[NT], w2v[NT];
    if (ACT == 1 || ACT == 3) {
#pragma unroll
        for (int nt = 0; nt < NT; ++nt)
            bv[nt] = bias[e * ND + wn * (BN / 2) + nt * 16 + lr];
    }
    if (ACT == 3) {
#pragma unroll
        for (int nt = 0; nt < NT; ++nt)
            w2v[nt] = W2[e * HID + wn * (BN / 2) + nt * 16 + lr];
    }

#pragma unroll
    for (int mt = 0; mt < 4; ++mt) {
#pragma unroll
        for (int r = 0; r < 4; ++r) {
            const int mrow = wm * 64 + mt * 16 + lq * 4 + r;
            const int m = m0 + mrow;
            const bool mok = (m < cnt);
            const int atom = mok ? list[m] : 0;
            float osum = 0.f;
#pragma unroll
            for (int nt = 0; nt < NT; ++nt) {
                const int n = wn * (BN / 2) + nt * 16 + lr;
                float val = acc[mt][nt][r];
                if (ACT == 1) {
                    val = tanh_fast(val + bv[nt]);
                } else if (ACT == 2) {
                    if (mok) {
                        float p = P[(size_t)atom * ND + n];
                        val *= (1.f - p * p);
                    }
                } else if (ACT == 3) {
                    float t = tanh_fast(val + bv[nt]);
                    osum += t * w2v[nt];
                    val = w2v[nt] * (1.f - t * t);   // dz1
                }
                if (mok) C[(size_t)atom * ND + n] = val;
            }
            if (ACT == 3) {
                // reduce osum across the 16 lanes (lr) sharing this row
                osum += __shfl_xor(osum, 1, 64);
                osum += __shfl_xor(osum, 2, 64);
                osum += __shfl_xor(osum, 4, 64);
                osum += __shfl_xor(osum, 8, 64);
                if (lr == 0) red[wn][mrow] = osum;
            }
        }
    }
    if (ACT == 3) {
        __syncthreads();
        if (tid < 128) {
            int m = m0 + tid;
            if (m < cnt) o_atom[list[m]] = red[0][tid] + red[1][tid] + b2[e];
        }
    }
}

// ---------------------------------------------------------------------------
// 3) Energy: one block/image; img sorted -> contiguous range; no atomics.
// ---------------------------------------------------------------------------
__global__ __launch_bounds__(256) void energy_kernel(
    const float* __restrict__ o_atom, const int* __restrict__ img,
    float* __restrict__ energy) {
    const int b = blockIdx.x;
    int lo, hi;
    {
        int l = 0, r = N_ATOMS;
        while (l < r) { int m = (l + r) >> 1; if (img[m] < b) l = m + 1; else r = m; }
        lo = l;
    }
    {
        int l = lo, r = N_ATOMS;
        while (l < r) { int m = (l + r) >> 1; if (img[m] < b + 1) l = m + 1; else r = m; }
        hi = l;
    }
    float s = 0.f;
    for (int i = lo + (int)threadIdx.x; i < hi; i += (int)blockDim.x) s += o_atom[i];
#pragma unroll
    for (int off = 32; off > 0; off >>= 1) s += __shfl_down(s, off, 64);
    __shared__ float red[4];
    if ((threadIdx.x & 63) == 0) red[threadIdx.x >> 6] = s;
    __syncthreads();
    if (threadIdx.x == 0) energy[b] = red[0] + red[1] + red[2] + red[3];
}

// ---------------------------------------------------------------------------
// 4) Forces — fabric-throughput-bound random gather+atomic (R4: 4/thread no
//    change). 8 nnz/thread, both index/val loads fully coalesced, 8
//    independent gathers in flight before the atomic tail.
// ---------------------------------------------------------------------------
__global__ __launch_bounds__(256) void forces_kernel(
    const int* __restrict__ rows, const int* __restrict__ cols,
    const float* __restrict__ vals, const float* __restrict__ g,
    float* __restrict__ F) {
    const int base = blockIdx.x * 2048;
    const int i0 = base + (int)threadIdx.x * 4;
    const int i1 = i0 + 1024;
    int4 r0, c0; float4 v0; bool ok0 = (i0 < NNZ);
    int4 r1, c1; float4 v1; bool ok1 = (i1 < NNZ);
    if (ok0) { r0 = *(const int4*)(rows + i0); c0 = *(const int4*)(cols + i0);
               v0 = *(const float4*)(vals + i0); }
    if (ok1) { r1 = *(const int4*)(rows + i1); c1 = *(const int4*)(cols + i1);
               v1 = *(const float4*)(vals + i1); }
    float g0, g1, g2, g3, g4, g5, g6, g7;
    if (ok0) { g0 = g[r0.x]; g1 = g[r0.y]; g2 = g[r0.z]; g3 = g[r0.w]; }
    if (ok1) { g4 = g[r1.x]; g5 = g[r1.y]; g6 = g[r1.z]; g7 = g[r1.w]; }
    if (ok0) {
        atomicAdd(&F[c0.x], -v0.x * g0);
        atomicAdd(&F[c0.y], -v0.y * g1);
        atomicAdd(&F[c0.z], -v0.z * g2);
        atomicAdd(&F[c0.w], -v0.w * g3);
    }
    if (ok1) {
        atomicAdd(&F[c1.x], -v1.x * g4);
        atomicAdd(&F[c1.y], -v1.y * g5);
        atomicAdd(&F[c1.z], -v1.z * g6);
        atomicAdd(&F[c1.w], -v1.w * g7);
    }
}

// ---------------------------------------------------------------------------
extern "C" void kernel_launch(void* const* d_in, const int* in_sizes, int n_in,
                              void* d_out, int out_size, void* d_ws, size_t ws_size,
                              hipStream_t stream) {
    const float* fp    = (const float*)d_in[0];
    const int*   Z     = (const int*)d_in[1];
    const int*   img   = (const int*)d_in[2];
    const int*   frows = (const int*)d_in[3];
    const int*   fcols = (const int*)d_in[4];
    const float* fvals = (const float*)d_in[5];
    const float* W0    = (const float*)d_in[6];
    const float* b0    = (const float*)d_in[7];
    const float* W1    = (const float*)d_in[8];
    const float* b1    = (const float*)d_in[9];
    const float* W2    = (const float*)d_in[10];
    const float* b2    = (const float*)d_in[11];

    float* out    = (float*)d_out;
    float* energy = out;             // [N_IMG]
    float* F      = out + N_IMG;     // [3*N_ATOMS]

    char* ws = (char*)d_ws;
    int*   counts = (int*)ws;                                   // 16 B
    int*   lists  = (int*)(ws + 1024);                          // 800 KB
    float* H0     = (float*)(ws + (1 << 20));                   // 50000*256 f32 (then dz0, in-place)
    float* DZ1    = (float*)(ws + (1 << 20) + 51200000);        // 50000*256 f32
    float* G      = (float*)(ws + (1 << 20) + 102400000);       // 50000*128 f32
    float* o_atom = (float*)(ws + (1 << 20) + 128000000);       // 50000 f32
    unsigned short* W0b = (unsigned short*)(ws + (1 << 20) + 128400000);
    unsigned short* W0T = W0b + N_ELEM * IN_DIM * HID;
    unsigned short* W1b = W0T + N_ELEM * IN_DIM * HID;
    unsigned short* W1T = W1b + N_ELEM * HID * HID;

    hipMemsetAsync(d_out, 0, (size_t)(N_IMG + 3 * N_ATOMS) * sizeof(float), stream);
    hipMemsetAsync(counts, 0, 4 * sizeof(int), stream);

    bucket_kernel<<<(N_ATOMS + 255) / 256, 256, 0, stream>>>(Z, counts, lists);
    prep_weights<<<(N_ELEM * HID * HID + 255) / 256, 256, 0, stream>>>(
        W0, W1, W0b, W0T, W1b, W1T);

    const int MT = (N_ATOMS + 127) / 128;   // 391

    // G1: H0 = tanh(fp @ W0 + b0)
    mfma_gemm<128, 256, 256, 1><<<dim3(MT, 1, N_ELEM), 256, 0, stream>>>(
        fp, W0T, b0, H0, nullptr, nullptr, nullptr, nullptr, counts, lists);
    // G2 (fused): DZ1 = W2*(1-tanh^2(H0@W1+b1)); o_atom = sum tanh*W2 + b2
    mfma_gemm<256, 256, 256, 3><<<dim3(MT, 1, N_ELEM), 256, 0, stream>>>(
        H0, W1T, b1, DZ1, nullptr, W2, b2, o_atom, counts, lists);

    energy_kernel<<<N_IMG, 256, 0, stream>>>(o_atom, img, energy);

    // G3: dz0 = (1-H0^2) * (DZ1 @ W1^T)   (in-place over H0)
    mfma_gemm<256, 256, 256, 2><<<dim3(MT, 1, N_ELEM), 256, 0, stream>>>(
        DZ1, W1b, nullptr, H0, H0, nullptr, nullptr, nullptr, counts, lists);
    // G4: g = dz0 @ W0^T
    mfma_gemm<256, 128, 128, 0><<<dim3(MT, 1, N_ELEM), 256, 0, stream>>>(
        H0, W0b, nullptr, G, nullptr, nullptr, nullptr, nullptr, counts, lists);

    // forces scatter
    forces_kernel<<<(NNZ + 2047) / 2048, 256, 0, stream>>>(frows, fcols, fvals, G, F);
}

// Round 6
// 346.040 us; speedup vs baseline: 2.5859x; 1.0600x over previous
//
#include <hip/hip_runtime.h>
#include <math.h>

#define N_ATOMS 50000
#define IN_DIM 128
#define HID 256
#define N_ELEM 4
#define N_IMG 500
#define NNZ 2000000

typedef __attribute__((ext_vector_type(8))) short bf16x8;   // 8 bf16 = 4 VGPRs
typedef __attribute__((ext_vector_type(4))) float f32x4;    // MFMA C/D frag

__device__ __forceinline__ int elem_of(int z) {
    return (z == 1) ? 0 : (z == 6) ? 1 : (z == 8) ? 2 : 3;
}

__device__ __forceinline__ unsigned short f2bf(float f) {   // RNE
    unsigned u = __float_as_uint(f);
    u += 0x7fffu + ((u >> 16) & 1u);
    return (unsigned short)(u >> 16);
}
__device__ __forceinline__ float bf2f(unsigned short u) {
    return __uint_as_float(((unsigned)u) << 16);
}
__device__ __forceinline__ float tanh_fast(float x) {
    float e = __expf(2.f * x);
    return (e - 1.f) / (e + 1.f);
}

// ---------------------------------------------------------------------------
// 1) Bucket atoms by element — LDS-aggregated (4 global atomics per block).
// ---------------------------------------------------------------------------
__global__ __launch_bounds__(256) void bucket_kernel(
    const int* __restrict__ Z, int* __restrict__ counts, int* __restrict__ lists) {
    __shared__ int lcnt[N_ELEM], lbase[N_ELEM];
    const int i = blockIdx.x * blockDim.x + threadIdx.x;
    if (threadIdx.x < N_ELEM) lcnt[threadIdx.x] = 0;
    __syncthreads();
    int e = -1, pos = 0;
    if (i < N_ATOMS) {
        e = elem_of(Z[i]);
        pos = atomicAdd(&lcnt[e], 1);
    }
    __syncthreads();
    if (threadIdx.x < N_ELEM)
        lbase[threadIdx.x] = atomicAdd(&counts[threadIdx.x], lcnt[threadIdx.x]);
    __syncthreads();
    if (i < N_ATOMS) lists[e * N_ATOMS + lbase[e] + pos] = i;
}

// ---------------------------------------------------------------------------
// 1b) Weight prep: bf16 plain ([e][k][n], B^T for backward) and transposed
//     ([e][n][k], B^T for forward).
// ---------------------------------------------------------------------------
__global__ __launch_bounds__(256) void prep_weights(
    const float* __restrict__ W0, const float* __restrict__ W1,
    unsigned short* __restrict__ W0b, unsigned short* __restrict__ W0T,
    unsigned short* __restrict__ W1b, unsigned short* __restrict__ W1T) {
    int t = blockIdx.x * 256 + threadIdx.x;
    if (t >= N_ELEM * HID * HID) return;
    int e = t >> 16;
    int rem = t & 65535;
    int k = rem >> 8, n = rem & 255;
    unsigned short w1 = f2bf(W1[t]);
    W1b[t] = w1;
    W1T[(e << 16) + (n << 8) + k] = w1;
    if (k < IN_DIM) {
        int i0 = e * (IN_DIM * HID) + rem;
        unsigned short w0 = f2bf(W0[i0]);
        W0b[i0] = w0;
        W0T[e * (IN_DIM * HID) + n * IN_DIM + k] = w0;
    }
}

// ---------------------------------------------------------------------------
// 2) MFMA GEMM over bucket-compacted rows. Tile 64(M) x BN(N), BN == ND.
//    R5 post-mortem: GEMMs latency-bound — gathered fp32 A + 16 f2bf/thread
//    per K-iter, ~1.5 blocks/CU, no pipelining. Now: A is bf16 and (except
//    G1) COMPACTED -> contiguous streaming loads, no conversion; BM=64 gives
//    ~3 blocks/CU; next K-chunk prefetched into registers before the MFMA
//    loop so global latency drains behind compute.
//    4 waves split over N: wave w covers cols [w*BN/4, ...). NT = BN/64 MFMA
//    col-tiles. mfma_f32_16x16x32_bf16; A/B frag [row=lane&15][k=(lane>>4)*8+j];
//    C/D col=lane&15, row=(lane>>4)*4+reg (m89-verified, working since R3).
//    LDS rows 40 shorts: frag reads spread 8/bank uniformly (b128 optimum).
//    ACT: 0 none; 1 tanh(acc+bias); 2 acc*(1-P^2), P bf16 compacted;
//         3 fused out_dz1: t=tanh(acc+bias); C=W2[n]*(1-t^2); o_atom=sum t*W2+b2.
//    GATHER_A: A rows via lists (fp32 fingerprints). SCATTER_C: C row=list[m].
// ---------------------------------------------------------------------------
template <int KD, int BN, int ACT, bool GATHER_A, bool A_FP32, bool SCATTER_C>
__global__ __launch_bounds__(256, 2) void mfma_gemm(
    const void* __restrict__ Ap,
    const unsigned short* __restrict__ Bt,
    const float* __restrict__ bias,
    unsigned short* __restrict__ Cb,
    const unsigned short* __restrict__ Pb,
    const float* __restrict__ W2, const float* __restrict__ b2,
    float* __restrict__ o_atom,
    const int* __restrict__ counts, const int* __restrict__ lists) {

    constexpr int NK = KD / 32;            // K-chunks
    constexpr int WCOLS = BN / 4;          // cols per wave
    constexpr int NT = WCOLS / 16;         // MFMA col-tiles per wave
    constexpr int BCH = BN / 64;           // B staging chunks per thread

    const int e = blockIdx.z;
    const int cnt = counts[e];
    const int m0 = blockIdx.x * 64;
    if (m0 >= cnt) return;
    int off = 0;
#pragma unroll
    for (int i = 0; i < N_ELEM; ++i) if (i < e) off += counts[i];
    const int* list = lists + e * N_ATOMS;
    const unsigned short* Be = Bt + (size_t)e * KD * BN;

    __shared__ short As[64 * 40];
    __shared__ short Bs[BN * 40];
    __shared__ float red[4][64];

    const int tid = threadIdx.x;
    const int lane = tid & 63;
    const int wv = tid >> 6;
    const int lr = lane & 15;
    const int lq = lane >> 4;

    // A staging: one 8-elem (16 B bf16 / 32 B fp32) chunk per thread
    const int arow_l = tid >> 2;           // 0..63
    const int aks = tid & 3;               // 0..3
    const int am = m0 + arow_l;
    const bool aok = (am < cnt);
    const float* arowF = nullptr;
    const unsigned short* arowH = nullptr;
    if (aok) {
        size_t rowidx = GATHER_A ? (size_t)list[am] : (size_t)(off + am);
        if (A_FP32) arowF = (const float*)Ap + rowidx * KD;
        else        arowH = (const unsigned short*)Ap + rowidx * KD;
    }

    f32x4 acc[4][NT];
#pragma unroll
    for (int mt = 0; mt < 4; ++mt)
#pragma unroll
        for (int nt = 0; nt < NT; ++nt)
#pragma unroll
            for (int j = 0; j < 4; ++j) acc[mt][nt][j] = 0.f;

    float4 a0p[2], a1p[2];
    bf16x8 ahp[2];
    bf16x8 bp[2][BCH];

    // prefetch chunk 0
    if (aok) {
        if (A_FP32) {
            a0p[0] = *(const float4*)(arowF + aks * 8);
            a1p[0] = *(const float4*)(arowF + aks * 8 + 4);
        } else {
            ahp[0] = *(const bf16x8*)(arowH + aks * 8);
        }
    }
#pragma unroll
    for (int t = 0; t < BCH; ++t) {
        int c = tid + 256 * t;
        int br = c & (BN - 1), bks = c / BN;
        bp[0][t] = *(const bf16x8*)(Be + (size_t)br * KD + bks * 8);
    }

#pragma unroll
    for (int ki = 0; ki < NK; ++ki) {
        const int cur = ki & 1, nx = cur ^ 1;
        // ---- store prefetched chunk to LDS
        bf16x8 av;
#pragma unroll
        for (int j = 0; j < 8; ++j) av[j] = 0;
        if (aok) {
            if (A_FP32) {
                av[0] = (short)f2bf(a0p[cur].x); av[1] = (short)f2bf(a0p[cur].y);
                av[2] = (short)f2bf(a0p[cur].z); av[3] = (short)f2bf(a0p[cur].w);
                av[4] = (short)f2bf(a1p[cur].x); av[5] = (short)f2bf(a1p[cur].y);
                av[6] = (short)f2bf(a1p[cur].z); av[7] = (short)f2bf(a1p[cur].w);
            } else {
                av = ahp[cur];
            }
        }
        *(bf16x8*)&As[arow_l * 40 + aks * 8] = av;
#pragma unroll
        for (int t = 0; t < BCH; ++t) {
            int c = tid + 256 * t;
            int br = c & (BN - 1), bks = c / BN;
            *(bf16x8*)&Bs[br * 40 + bks * 8] = bp[cur][t];
        }
        __syncthreads();
        // ---- prefetch next chunk (drains during MFMA below)
        if (ki + 1 < NK) {
            const int k0n = (ki + 1) * 32;
            if (aok) {
                if (A_FP32) {
                    a0p[nx] = *(const float4*)(arowF + k0n + aks * 8);
                    a1p[nx] = *(const float4*)(arowF + k0n + aks * 8 + 4);
                } else {
                    ahp[nx] = *(const bf16x8*)(arowH + k0n + aks * 8);
                }
            }
#pragma unroll
            for (int t = 0; t < BCH; ++t) {
                int c = tid + 256 * t;
                int br = c & (BN - 1), bks = c / BN;
                bp[nx][t] = *(const bf16x8*)(Be + (size_t)br * KD + k0n + bks * 8);
            }
        }
        // ---- frags + MFMA
        bf16x8 af[4], bfr[NT];
#pragma unroll
        for (int mt = 0; mt < 4; ++mt)
            af[mt] = *(const bf16x8*)&As[(mt * 16 + lr) * 40 + lq * 8];
#pragma unroll
        for (int nt = 0; nt < NT; ++nt)
            bfr[nt] = *(const bf16x8*)&Bs[(wv * WCOLS + nt * 16 + lr) * 40 + lq * 8];
#pragma unroll
        for (int mt = 0; mt < 4; ++mt)
#pragma unroll
            for (int nt = 0; nt < NT; ++nt)
                acc[mt][nt] = __builtin_amdgcn_mfma_f32_16x16x32_bf16(
                    af[mt], bfr[nt], acc[mt][nt], 0, 0, 0);
        __syncthreads();
    }

    // ---- epilogue
    float bv[NT], w2v[NT];
    if (ACT == 1 || ACT == 3) {
#pragma unroll
        for (int nt = 0; nt < NT; ++nt)
            bv[nt] = bias[e * BN + wv * WCOLS + nt * 16 + lr];
    }
    if (ACT == 3) {
#pragma unroll
        for (int nt = 0; nt < NT; ++nt)
            w2v[nt] = W2[e * HID + wv * WCOLS + nt * 16 + lr];
    }

#pragma unroll
    for (int mt = 0; mt < 4; ++mt) {
#pragma unroll
        for (int r = 0; r < 4; ++r) {
            const int row = mt * 16 + lq * 4 + r;
            const int m = m0 + row;
            const bool mok = (m < cnt);
            size_t crow = 0;
            if (mok) crow = (size_t)(SCATTER_C ? list[m] : (off + m)) * BN;
            float osum = 0.f;
#pragma unroll
            for (int nt = 0; nt < NT; ++nt) {
                const int n = wv * WCOLS + nt * 16 + lr;
                float val = acc[mt][nt][r];
                if (ACT == 1) {
                    val = tanh_fast(val + bv[nt]);
                } else if (ACT == 2) {
                    if (mok) {
                        float p = bf2f(Pb[(size_t)(off + m) * BN + n]);
                        val *= (1.f - p * p);
                    }
                } else if (ACT == 3) {
                    float t = tanh_fast(val + bv[nt]);
                    osum += t * w2v[nt];
                    val = w2v[nt] * (1.f - t * t);   // dz1
                }
                if (mok) Cb[crow + n] = f2bf(val);
            }
            if (ACT == 3) {
                osum += __shfl_xor(osum, 1, 64);
                osum += __shfl_xor(osum, 2, 64);
                osum += __shfl_xor(osum, 4, 64);
                osum += __shfl_xor(osum, 8, 64);
                if (lr == 0) red[wv][row] = osum;
            }
        }
    }
    if (ACT == 3) {
        __syncthreads();
        if (tid < 64) {
            int m = m0 + tid;
            if (m < cnt)
                o_atom[list[m]] = red[0][tid] + red[1][tid] + red[2][tid] +
                                  red[3][tid] + b2[e];
        }
    }
}

// ---------------------------------------------------------------------------
// 3) Energy: one block/image; img sorted -> contiguous range; no atomics.
// ---------------------------------------------------------------------------
__global__ __launch_bounds__(256) void energy_kernel(
    const float* __restrict__ o_atom, const int* __restrict__ img,
    float* __restrict__ energy) {
    const int b = blockIdx.x;
    int lo, hi;
    {
        int l = 0, r = N_ATOMS;
        while (l < r) { int m = (l + r) >> 1; if (img[m] < b) l = m + 1; else r = m; }
        lo = l;
    }
    {
        int l = lo, r = N_ATOMS;
        while (l < r) { int m = (l + r) >> 1; if (img[m] < b + 1) l = m + 1; else r = m; }
        hi = l;
    }
    float s = 0.f;
    for (int i = lo + (int)threadIdx.x; i < hi; i += (int)blockDim.x) s += o_atom[i];
#pragma unroll
    for (int off = 32; off > 0; off >>= 1) s += __shfl_down(s, off, 64);
    __shared__ float red[4];
    if ((threadIdx.x & 63) == 0) red[threadIdx.x >> 6] = s;
    __syncthreads();
    if (threadIdx.x == 0) energy[b] = red[0] + red[1] + red[2] + red[3];
}

// ---------------------------------------------------------------------------
// 4) Forces — R5 post-mortem: 8/thread halved parallelism and regressed;
//    back to R4's 4/thread x 1954-block shape. g now bf16 (12.8 MB working
//    set -> better L2 residency for the random gather).
// ---------------------------------------------------------------------------
__global__ __launch_bounds__(256) void forces_kernel(
    const int* __restrict__ rows, const int* __restrict__ cols,
    const float* __restrict__ vals, const unsigned short* __restrict__ g,
    float* __restrict__ F) {
    const int i0 = (blockIdx.x * 256 + threadIdx.x) * 4;
    if (i0 >= NNZ) return;
    int4 r = *(const int4*)(rows + i0);
    int4 c = *(const int4*)(cols + i0);
    float4 v = *(const float4*)(vals + i0);
    float g0 = bf2f(g[r.x]), g1 = bf2f(g[r.y]), g2 = bf2f(g[r.z]), g3 = bf2f(g[r.w]);
    atomicAdd(&F[c.x], -v.x * g0);
    atomicAdd(&F[c.y], -v.y * g1);
    atomicAdd(&F[c.z], -v.z * g2);
    atomicAdd(&F[c.w], -v.w * g3);
}

// ---------------------------------------------------------------------------
extern "C" void kernel_launch(void* const* d_in, const int* in_sizes, int n_in,
                              void* d_out, int out_size, void* d_ws, size_t ws_size,
                              hipStream_t stream) {
    const float* fp    = (const float*)d_in[0];
    const int*   Z     = (const int*)d_in[1];
    const int*   img   = (const int*)d_in[2];
    const int*   frows = (const int*)d_in[3];
    const int*   fcols = (const int*)d_in[4];
    const float* fvals = (const float*)d_in[5];
    const float* W0    = (const float*)d_in[6];
    const float* b0    = (const float*)d_in[7];
    const float* W1    = (const float*)d_in[8];
    const float* b1    = (const float*)d_in[9];
    const float* W2    = (const float*)d_in[10];
    const float* b2    = (const float*)d_in[11];

    float* out    = (float*)d_out;
    float* energy = out;             // [N_IMG]
    float* F      = out + N_IMG;     // [3*N_ATOMS]

    char* ws = (char*)d_ws;
    int*   counts = (int*)ws;                                   // 16 B
    int*   lists  = (int*)(ws + 1024);                          // 800 KB
    char*  base   = ws + (1 << 20);
    unsigned short* H0c  = (unsigned short*)(base);              // 50000*256 bf16 (compacted)
    unsigned short* DZ1c = (unsigned short*)(base + 26000000);   // 50000*256 bf16
    unsigned short* dz0c = (unsigned short*)(base + 52000000);   // 50000*256 bf16
    unsigned short* Gb   = (unsigned short*)(base + 78000000);   // 50000*128 bf16 (atom order)
    float* o_atom        = (float*)(base + 91000000);            // 50000 f32
    unsigned short* W0b  = (unsigned short*)(base + 92000000);   // [e][k][n] 4*128*256
    unsigned short* W0T  = W0b + N_ELEM * IN_DIM * HID;          // [e][n][k]
    unsigned short* W1b  = W0T + N_ELEM * IN_DIM * HID;          // [e][k][n] 4*256*256
    unsigned short* W1T  = W1b + N_ELEM * HID * HID;             // [e][n][k]

    hipMemsetAsync(d_out, 0, (size_t)(N_IMG + 3 * N_ATOMS) * sizeof(float), stream);
    hipMemsetAsync(counts, 0, 4 * sizeof(int), stream);

    bucket_kernel<<<(N_ATOMS + 255) / 256, 256, 0, stream>>>(Z, counts, lists);
    prep_weights<<<(N_ELEM * HID * HID + 255) / 256, 256, 0, stream>>>(
        W0, W1, W0b, W0T, W1b, W1T);

    const int MT = (N_ATOMS + 63) / 64;   // 782; ~196/element active

    // G1: H0c = tanh(fp @ W0 + b0)            A fp32 gathered; C compacted
    mfma_gemm<128, 256, 1, true, true, false><<<dim3(MT, 1, N_ELEM), 256, 0, stream>>>(
        fp, W0T, b0, H0c, nullptr, nullptr, nullptr, nullptr, counts, lists);
    // G2 (fused): DZ1c = W2*(1-tanh^2(H0c@W1+b1)); o_atom = sum tanh*W2 + b2
    mfma_gemm<256, 256, 3, false, false, false><<<dim3(MT, 1, N_ELEM), 256, 0, stream>>>(
        H0c, W1T, b1, DZ1c, nullptr, W2, b2, o_atom, counts, lists);

    energy_kernel<<<N_IMG, 256, 0, stream>>>(o_atom, img, energy);

    // G3: dz0c = (1-H0c^2) * (DZ1c @ W1^T)
    mfma_gemm<256, 256, 2, false, false, false><<<dim3(MT, 1, N_ELEM), 256, 0, stream>>>(
        DZ1c, W1b, nullptr, dz0c, H0c, nullptr, nullptr, nullptr, counts, lists);
    // G4: Gb = dz0c @ W0^T   (C scattered to atom order for forces)
    mfma_gemm<256, 128, 0, false, false, true><<<dim3(MT, 1, N_ELEM), 256, 0, stream>>>(
        dz0c, W0b, nullptr, Gb, nullptr, nullptr, nullptr, nullptr, counts, lists);

    // forces scatter
    forces_kernel<<<(NNZ / 4 + 255) / 256, 256, 0, stream>>>(frows, fcols, fvals, Gb, F);
}

// Round 7
// 338.046 us; speedup vs baseline: 2.6471x; 1.0236x over previous
//
#include <hip/hip_runtime.h>
#include <math.h>

#define N_ATOMS 50000
#define IN_DIM 128
#define HID 256
#define N_ELEM 4
#define N_IMG 500
#define NNZ 2000000

typedef __attribute__((ext_vector_type(8))) short bf16x8;   // 8 bf16 = 4 VGPRs
typedef __attribute__((ext_vector_type(4))) float f32x4;    // MFMA C/D frag

__device__ __forceinline__ int elem_of(int z) {
    return (z == 1) ? 0 : (z == 6) ? 1 : (z == 8) ? 2 : 3;
}

__device__ __forceinline__ unsigned short f2bf(float f) {   // RNE
    unsigned u = __float_as_uint(f);
    u += 0x7fffu + ((u >> 16) & 1u);
    return (unsigned short)(u >> 16);
}
__device__ __forceinline__ float bf2f(unsigned short u) {
    return __uint_as_float(((unsigned)u) << 16);
}
__device__ __forceinline__ float tanh_fast(float x) {
    float e = __expf(2.f * x);
    return (e - 1.f) / (e + 1.f);
}

// ---------------------------------------------------------------------------
// 1) Bucket atoms by element — LDS-aggregated (4 global atomics per block).
// ---------------------------------------------------------------------------
__global__ __launch_bounds__(256) void bucket_kernel(
    const int* __restrict__ Z, int* __restrict__ counts, int* __restrict__ lists) {
    __shared__ int lcnt[N_ELEM], lbase[N_ELEM];
    const int i = blockIdx.x * blockDim.x + threadIdx.x;
    if (threadIdx.x < N_ELEM) lcnt[threadIdx.x] = 0;
    __syncthreads();
    int e = -1, pos = 0;
    if (i < N_ATOMS) {
        e = elem_of(Z[i]);
        pos = atomicAdd(&lcnt[e], 1);
    }
    __syncthreads();
    if (threadIdx.x < N_ELEM)
        lbase[threadIdx.x] = atomicAdd(&counts[threadIdx.x], lcnt[threadIdx.x]);
    __syncthreads();
    if (i < N_ATOMS) lists[e * N_ATOMS + lbase[e] + pos] = i;
}

// ---------------------------------------------------------------------------
// 1b) Weight prep: bf16 plain ([e][k][n], B^T for backward) and transposed
//     ([e][n][k], B^T for forward).
// ---------------------------------------------------------------------------
__global__ __launch_bounds__(256) void prep_weights(
    const float* __restrict__ W0, const float* __restrict__ W1,
    unsigned short* __restrict__ W0b, unsigned short* __restrict__ W0T,
    unsigned short* __restrict__ W1b, unsigned short* __restrict__ W1T) {
    int t = blockIdx.x * 256 + threadIdx.x;
    if (t >= N_ELEM * HID * HID) return;
    int e = t >> 16;
    int rem = t & 65535;
    int k = rem >> 8, n = rem & 255;
    unsigned short w1 = f2bf(W1[t]);
    W1b[t] = w1;
    W1T[(e << 16) + (n << 8) + k] = w1;
    if (k < IN_DIM) {
        int i0 = e * (IN_DIM * HID) + rem;
        unsigned short w0 = f2bf(W0[i0]);
        W0b[i0] = w0;
        W0T[e * (IN_DIM * HID) + n * IN_DIM + k] = w0;
    }
}

// ---------------------------------------------------------------------------
// 2) FULLY-FUSED per-atom MLP fwd+bwd. R6 post-mortem: the 4 separate GEMMs
//    held ~200us — intermediates (H0/DZ1/dz0, ~154 MB round-trip) through HBM
//    at ~1.5 TB/s effective + 4x launch/drain. Here one block owns 32 atom
//    rows end-to-end; h0 and dz1 live in LDS chunk-major tiles; dz0
//    overwrites h0 in-place (same thread, same slot); only fp (gathered),
//    o_atom and g ever touch global. HBM traffic drops ~236 MB -> ~39 MB.
//    Tiles are 8 stacked 32x36-stride mini-blocks so MFMA frag reads keep the
//    same bank pattern as the staging buffers (2-way max = free, m136).
//    Stages (all mfma_f32_16x16x32_bf16, A/B frag [row=lane&15][k=quad*8+j],
//    C/D col=lane&15 row=quad*4+reg, m89-verified, in use since R3):
//      S1: h0 = tanh(fp@W0T + b0)              -> tileH
//      S2: t = tanh(h0@W1T + b1); o=sum t*W2   -> o_atom; dz1=W2(1-t^2) -> tileD
//      S3: dz0 = (dz1@W1b) * (1-h0^2)          -> tileH (in-place)
//      S4: g = dz0@W0b                         -> tileD -> coalesced Gb scatter
// ---------------------------------------------------------------------------
__global__ __launch_bounds__(256, 2) void fused_mlp(
    const float* __restrict__ fp,
    const unsigned short* __restrict__ W0T,   // [e][n=256][k=128]
    const unsigned short* __restrict__ W1T,   // [e][n=256][k=256]
    const unsigned short* __restrict__ W1b,   // [e][n=256][k=256] (plain W1)
    const unsigned short* __restrict__ W0b,   // [e][n=128][k=256] (plain W0)
    const float* __restrict__ b0, const float* __restrict__ b1,
    const float* __restrict__ W2, const float* __restrict__ b2,
    float* __restrict__ o_atom,
    unsigned short* __restrict__ Gb,
    const int* __restrict__ counts, const int* __restrict__ lists) {

    const int e = blockIdx.z;
    const int cnt = counts[e];
    const int m0 = blockIdx.x * 32;
    if (m0 >= cnt) return;
    const int* list = lists + e * N_ATOMS;

    __shared__ short As[32 * 36];          // stage-1 A staging (one k-chunk)
    __shared__ short Bs[256 * 36];         // B staging (one k-chunk, <=256 rows)
    __shared__ short tH[8 * 32 * 36];      // h0 tile, chunk-major; later dz0
    __shared__ short tD[8 * 32 * 36];      // dz1 tile; later g-transpose
    __shared__ float red[4][32];

    const int tid = threadIdx.x;
    const int lane = tid & 63;
    const int wv = tid >> 6;
    const int lr = lane & 15;
    const int lq = lane >> 4;

    const unsigned short* W0Te = W0T + (size_t)e * HID * IN_DIM;
    const unsigned short* W1Te = W1T + (size_t)e * HID * HID;
    const unsigned short* W1be = W1b + (size_t)e * HID * HID;
    const unsigned short* W0be = W0b + (size_t)e * IN_DIM * HID;

    // stage-1 A gather mapping: threads 0..127 each own (row = tid>>2, ks = tid&3)
    const int arow_l = tid >> 2;
    const int aks = tid & 3;
    const bool athr = (tid < 128);
    const bool aok = athr && (m0 + arow_l < cnt);
    const float* arowF = aok ? (fp + (size_t)list[m0 + arow_l] * IN_DIM) : nullptr;

    f32x4 acc[2][4];
    bf16x8 bp[2][4];
    float4 a0p[2], a1p[2];
    bf16x8 af[2], bfr[4];

#define ZERO_ACC()                                                        \
    _Pragma("unroll") for (int mt = 0; mt < 2; ++mt)                      \
        _Pragma("unroll") for (int nt = 0; nt < 4; ++nt)                  \
            _Pragma("unroll") for (int j = 0; j < 4; ++j) acc[mt][nt][j] = 0.f;

    // =================== Stage 1: z0 = fp @ W0T  (K = 128, NK = 4) =========
    ZERO_ACC();
    if (aok) {
        a0p[0] = *(const float4*)(arowF + aks * 8);
        a1p[0] = *(const float4*)(arowF + aks * 8 + 4);
    }
#pragma unroll
    for (int t = 0; t < 4; ++t)
        bp[0][t] = *(const bf16x8*)(W0Te + (size_t)tid * IN_DIM + t * 8);

#pragma unroll
    for (int ki = 0; ki < 4; ++ki) {
        const int cur = ki & 1, nx = cur ^ 1;
        if (athr) {
            bf16x8 av;
#pragma unroll
            for (int j = 0; j < 8; ++j) av[j] = 0;
            if (aok) {
                av[0] = (short)f2bf(a0p[cur].x); av[1] = (short)f2bf(a0p[cur].y);
                av[2] = (short)f2bf(a0p[cur].z); av[3] = (short)f2bf(a0p[cur].w);
                av[4] = (short)f2bf(a1p[cur].x); av[5] = (short)f2bf(a1p[cur].y);
                av[6] = (short)f2bf(a1p[cur].z); av[7] = (short)f2bf(a1p[cur].w);
            }
            *(bf16x8*)&As[arow_l * 36 + aks * 8] = av;
        }
#pragma unroll
        for (int t = 0; t < 4; ++t)
            *(bf16x8*)&Bs[tid * 36 + t * 8] = bp[cur][t];
        __syncthreads();
        if (ki < 3) {
            const int k0n = (ki + 1) * 32;
            if (aok) {
                a0p[nx] = *(const float4*)(arowF + k0n + aks * 8);
                a1p[nx] = *(const float4*)(arowF + k0n + aks * 8 + 4);
            }
#pragma unroll
            for (int t = 0; t < 4; ++t)
                bp[nx][t] = *(const bf16x8*)(W0Te + (size_t)tid * IN_DIM + k0n + t * 8);
        }
#pragma unroll
        for (int mt = 0; mt < 2; ++mt)
            af[mt] = *(const bf16x8*)&As[(mt * 16 + lr) * 36 + lq * 8];
#pragma unroll
        for (int nt = 0; nt < 4; ++nt)
            bfr[nt] = *(const bf16x8*)&Bs[(wv * 64 + nt * 16 + lr) * 36 + lq * 8];
#pragma unroll
        for (int mt = 0; mt < 2; ++mt)
#pragma unroll
            for (int nt = 0; nt < 4; ++nt)
                acc[mt][nt] = __builtin_amdgcn_mfma_f32_16x16x32_bf16(
                    af[mt], bfr[nt], acc[mt][nt], 0, 0, 0);
        __syncthreads();
    }
    // epilogue 1: h0 = tanh(z0 + b0) -> tH (chunk-major)
    {
        float bv[4];
#pragma unroll
        for (int nt = 0; nt < 4; ++nt)
            bv[nt] = b0[e * HID + wv * 64 + nt * 16 + lr];
#pragma unroll
        for (int mt = 0; mt < 2; ++mt)
#pragma unroll
            for (int r = 0; r < 4; ++r) {
                const int row = mt * 16 + lq * 4 + r;
#pragma unroll
                for (int nt = 0; nt < 4; ++nt) {
                    const int n = wv * 64 + nt * 16 + lr;
                    float t = tanh_fast(acc[mt][nt][r] + bv[nt]);
                    tH[(n >> 5) * 1152 + row * 36 + (n & 31)] = (short)f2bf(t);
                }
            }
    }
    __syncthreads();

    // =================== Stage 2: z1 = h0 @ W1T  (K = 256, NK = 8) =========
    ZERO_ACC();
#pragma unroll
    for (int t = 0; t < 4; ++t)
        bp[0][t] = *(const bf16x8*)(W1Te + (size_t)tid * HID + t * 8);
#pragma unroll
    for (int ki = 0; ki < 8; ++ki) {
        const int cur = ki & 1, nx = cur ^ 1;
#pragma unroll
        for (int t = 0; t < 4; ++t)
            *(bf16x8*)&Bs[tid * 36 + t * 8] = bp[cur][t];
        __syncthreads();
        if (ki < 7) {
            const int k0n = (ki + 1) * 32;
#pragma unroll
            for (int t = 0; t < 4; ++t)
                bp[nx][t] = *(const bf16x8*)(W1Te + (size_t)tid * HID + k0n + t * 8);
        }
#pragma unroll
        for (int mt = 0; mt < 2; ++mt)
            af[mt] = *(const bf16x8*)&tH[ki * 1152 + (mt * 16 + lr) * 36 + lq * 8];
#pragma unroll
        for (int nt = 0; nt < 4; ++nt)
            bfr[nt] = *(const bf16x8*)&Bs[(wv * 64 + nt * 16 + lr) * 36 + lq * 8];
#pragma unroll
        for (int mt = 0; mt < 2; ++mt)
#pragma unroll
            for (int nt = 0; nt < 4; ++nt)
                acc[mt][nt] = __builtin_amdgcn_mfma_f32_16x16x32_bf16(
                    af[mt], bfr[nt], acc[mt][nt], 0, 0, 0);
        __syncthreads();
    }
    // epilogue 2: t = tanh(z1+b1); o = sum t*W2 -> o_atom; dz1 = W2(1-t^2) -> tD
    {
        float bv[4], w2v[4];
#pragma unroll
        for (int nt = 0; nt < 4; ++nt) {
            bv[nt]  = b1[e * HID + wv * 64 + nt * 16 + lr];
            w2v[nt] = W2[e * HID + wv * 64 + nt * 16 + lr];
        }
#pragma unroll
        for (int mt = 0; mt < 2; ++mt)
#pragma unroll
            for (int r = 0; r < 4; ++r) {
                const int row = mt * 16 + lq * 4 + r;
                float osum = 0.f;
#pragma unroll
                for (int nt = 0; nt < 4; ++nt) {
                    const int n = wv * 64 + nt * 16 + lr;
                    float t = tanh_fast(acc[mt][nt][r] + bv[nt]);
                    osum += t * w2v[nt];
                    tD[(n >> 5) * 1152 + row * 36 + (n & 31)] =
                        (short)f2bf(w2v[nt] * (1.f - t * t));
                }
                osum += __shfl_xor(osum, 1, 64);
                osum += __shfl_xor(osum, 2, 64);
                osum += __shfl_xor(osum, 4, 64);
                osum += __shfl_xor(osum, 8, 64);
                if (lr == 0) red[wv][row] = osum;
            }
    }
    __syncthreads();
    if (tid < 32) {
        int m = m0 + tid;
        if (m < cnt)
            o_atom[list[m]] = red[0][tid] + red[1][tid] + red[2][tid] +
                              red[3][tid] + b2[e];
    }

    // =================== Stage 3: dz0 = (dz1 @ W1b) * (1-h0^2) =============
    ZERO_ACC();
#pragma unroll
    for (int t = 0; t < 4; ++t)
        bp[0][t] = *(const bf16x8*)(W1be + (size_t)tid * HID + t * 8);
#pragma unroll
    for (int ki = 0; ki < 8; ++ki) {
        const int cur = ki & 1, nx = cur ^ 1;
#pragma unroll
        for (int t = 0; t < 4; ++t)
            *(bf16x8*)&Bs[tid * 36 + t * 8] = bp[cur][t];
        __syncthreads();
        if (ki < 7) {
            const int k0n = (ki + 1) * 32;
#pragma unroll
            for (int t = 0; t < 4; ++t)
                bp[nx][t] = *(const bf16x8*)(W1be + (size_t)tid * HID + k0n + t * 8);
        }
#pragma unroll
        for (int mt = 0; mt < 2; ++mt)
            af[mt] = *(const bf16x8*)&tD[ki * 1152 + (mt * 16 + lr) * 36 + lq * 8];
#pragma unroll
        for (int nt = 0; nt < 4; ++nt)
            bfr[nt] = *(const bf16x8*)&Bs[(wv * 64 + nt * 16 + lr) * 36 + lq * 8];
#pragma unroll
        for (int mt = 0; mt < 2; ++mt)
#pragma unroll
            for (int nt = 0; nt < 4; ++nt)
                acc[mt][nt] = __builtin_amdgcn_mfma_f32_16x16x32_bf16(
                    af[mt], bfr[nt], acc[mt][nt], 0, 0, 0);
        __syncthreads();
    }
    // epilogue 3: read h0, dz0 = acc*(1-h0^2), overwrite tH slot (same thread)
#pragma unroll
    for (int mt = 0; mt < 2; ++mt)
#pragma unroll
        for (int r = 0; r < 4; ++r) {
            const int row = mt * 16 + lq * 4 + r;
#pragma unroll
            for (int nt = 0; nt < 4; ++nt) {
                const int n = wv * 64 + nt * 16 + lr;
                const int a = (n >> 5) * 1152 + row * 36 + (n & 31);
                float h = bf2f((unsigned short)tH[a]);
                tH[a] = (short)f2bf(acc[mt][nt][r] * (1.f - h * h));
            }
        }
    __syncthreads();

    // =================== Stage 4: g = dz0 @ W0b  (N = 128, NT = 2) =========
    {
        f32x4 acc4[2][2];
#pragma unroll
        for (int mt = 0; mt < 2; ++mt)
#pragma unroll
            for (int nt = 0; nt < 2; ++nt)
#pragma unroll
                for (int j = 0; j < 4; ++j) acc4[mt][nt][j] = 0.f;

        const int br = tid & 127;
        const int bk0 = tid >> 7;            // 0 or 1; handles bks {bk0, bk0+2}
        bf16x8 bq[2][2];
#pragma unroll
        for (int t = 0; t < 2; ++t)
            bq[0][t] = *(const bf16x8*)(W0be + (size_t)br * HID + (bk0 + 2 * t) * 8);
#pragma unroll
        for (int ki = 0; ki < 8; ++ki) {
            const int cur = ki & 1, nx = cur ^ 1;
#pragma unroll
            for (int t = 0; t < 2; ++t)
                *(bf16x8*)&Bs[br * 36 + (bk0 + 2 * t) * 8] = bq[cur][t];
            __syncthreads();
            if (ki < 7) {
                const int k0n = (ki + 1) * 32;
#pragma unroll
                for (int t = 0; t < 2; ++t)
                    bq[nx][t] = *(const bf16x8*)(W0be + (size_t)br * HID + k0n + (bk0 + 2 * t) * 8);
            }
            bf16x8 af4[2], bf4[2];
#pragma unroll
            for (int mt = 0; mt < 2; ++mt)
                af4[mt] = *(const bf16x8*)&tH[ki * 1152 + (mt * 16 + lr) * 36 + lq * 8];
#pragma unroll
            for (int nt = 0; nt < 2; ++nt)
                bf4[nt] = *(const bf16x8*)&Bs[(wv * 32 + nt * 16 + lr) * 36 + lq * 8];
#pragma unroll
            for (int mt = 0; mt < 2; ++mt)
#pragma unroll
                for (int nt = 0; nt < 2; ++nt)
                    acc4[mt][nt] = __builtin_amdgcn_mfma_f32_16x16x32_bf16(
                        af4[mt], bf4[nt], acc4[mt][nt], 0, 0, 0);
            __syncthreads();
        }
        // epilogue 4: g -> tD (chunk-major), then coalesced bf16x8 scatter
#pragma unroll
        for (int mt = 0; mt < 2; ++mt)
#pragma unroll
            for (int r = 0; r < 4; ++r) {
                const int row = mt * 16 + lq * 4 + r;
#pragma unroll
                for (int nt = 0; nt < 2; ++nt) {
                    const int n = wv * 32 + nt * 16 + lr;
                    tD[(n >> 5) * 1152 + row * 36 + (n & 31)] =
                        (short)f2bf(acc4[mt][nt][r]);
                }
            }
        __syncthreads();
#pragma unroll
        for (int t = 0; t < 2; ++t) {
            const int c = tid + 256 * t;         // 0..511
            const int row = c >> 4;              // 0..31
            const int pos = (c & 15) * 8;        // 0..120
            const int m = m0 + row;
            if (m < cnt) {
                bf16x8 v = *(const bf16x8*)&tD[(pos >> 5) * 1152 + row * 36 + (pos & 31)];
                *(bf16x8*)(Gb + (size_t)list[m] * IN_DIM + pos) = v;
            }
        }
    }
#undef ZERO_ACC
}

// ---------------------------------------------------------------------------
// 3) Energy: one block/image; img sorted -> contiguous range; no atomics.
// ---------------------------------------------------------------------------
__global__ __launch_bounds__(256) void energy_kernel(
    const float* __restrict__ o_atom, const int* __restrict__ img,
    float* __restrict__ energy) {
    const int b = blockIdx.x;
    int lo, hi;
    {
        int l = 0, r = N_ATOMS;
        while (l < r) { int m = (l + r) >> 1; if (img[m] < b) l = m + 1; else r = m; }
        lo = l;
    }
    {
        int l = lo, r = N_ATOMS;
        while (l < r) { int m = (l + r) >> 1; if (img[m] < b + 1) l = m + 1; else r = m; }
        hi = l;
    }
    float s = 0.f;
    for (int i = lo + (int)threadIdx.x; i < hi; i += (int)blockDim.x) s += o_atom[i];
#pragma unroll
    for (int off = 32; off > 0; off >>= 1) s += __shfl_down(s, off, 64);
    __shared__ float red[4];
    if ((threadIdx.x & 63) == 0) red[threadIdx.x >> 6] = s;
    __syncthreads();
    if (threadIdx.x == 0) energy[b] = red[0] + red[1] + red[2] + red[3];
}

// ---------------------------------------------------------------------------
// 4) Forces — structural floor ~110us: 24 MB stream + ~77 MB gather lines +
//    62 MB atomic write-through at ~1.5 TB/s fabric. R6 shape (4/thread,
//    1954 blocks, bf16 g) kept.
// ---------------------------------------------------------------------------
__global__ __launch_bounds__(256) void forces_kernel(
    const int* __restrict__ rows, const int* __restrict__ cols,
    const float* __restrict__ vals, const unsigned short* __restrict__ g,
    float* __restrict__ F) {
    const int i0 = (blockIdx.x * 256 + threadIdx.x) * 4;
    if (i0 >= NNZ) return;
    int4 r = *(const int4*)(rows + i0);
    int4 c = *(const int4*)(cols + i0);
    float4 v = *(const float4*)(vals + i0);
    float g0 = bf2f(g[r.x]), g1 = bf2f(g[r.y]), g2 = bf2f(g[r.z]), g3 = bf2f(g[r.w]);
    atomicAdd(&F[c.x], -v.x * g0);
    atomicAdd(&F[c.y], -v.y * g1);
    atomicAdd(&F[c.z], -v.z * g2);
    atomicAdd(&F[c.w], -v.w * g3);
}

// ---------------------------------------------------------------------------
extern "C" void kernel_launch(void* const* d_in, const int* in_sizes, int n_in,
                              void* d_out, int out_size, void* d_ws, size_t ws_size,
                              hipStream_t stream) {
    const float* fp    = (const float*)d_in[0];
    const int*   Z     = (const int*)d_in[1];
    const int*   img   = (const int*)d_in[2];
    const int*   frows = (const int*)d_in[3];
    const int*   fcols = (const int*)d_in[4];
    const float* fvals = (const float*)d_in[5];
    const float* W0    = (const float*)d_in[6];
    const float* b0    = (const float*)d_in[7];
    const float* W1    = (const float*)d_in[8];
    const float* b1    = (const float*)d_in[9];
    const float* W2    = (const float*)d_in[10];
    const float* b2    = (const float*)d_in[11];

    float* out    = (float*)d_out;
    float* energy = out;             // [N_IMG]
    float* F      = out + N_IMG;     // [3*N_ATOMS]

    char* ws = (char*)d_ws;
    int*   counts = (int*)ws;                                   // 16 B
    int*   lists  = (int*)(ws + 1024);                          // 800 KB
    char*  base   = ws + (1 << 20);
    unsigned short* Gb   = (unsigned short*)(base);              // 50000*128 bf16 (atom order)
    float* o_atom        = (float*)(base + 13000000);            // 50000 f32
    unsigned short* W0b  = (unsigned short*)(base + 14000000);   // [e][in][hid]
    unsigned short* W0T  = W0b + N_ELEM * IN_DIM * HID;          // [e][hid][in]
    unsigned short* W1b  = W0T + N_ELEM * IN_DIM * HID;          // [e][k][n]
    unsigned short* W1T  = W1b + N_ELEM * HID * HID;             // [e][n][k]

    hipMemsetAsync(d_out, 0, (size_t)(N_IMG + 3 * N_ATOMS) * sizeof(float), stream);
    hipMemsetAsync(counts, 0, 4 * sizeof(int), stream);

    bucket_kernel<<<(N_ATOMS + 255) / 256, 256, 0, stream>>>(Z, counts, lists);
    prep_weights<<<(N_ELEM * HID * HID + 255) / 256, 256, 0, stream>>>(
        W0, W1, W0b, W0T, W1b, W1T);

    const int MT = (N_ATOMS + 31) / 32;   // 1563; ~391/element active

    fused_mlp<<<dim3(MT, 1, N_ELEM), 256, 0, stream>>>(
        fp, W0T, W1T, W1b, W0b, b0, b1, W2, b2, o_atom, Gb, counts, lists);

    energy_kernel<<<N_IMG, 256, 0, stream>>>(o_atom, img, energy);

    forces_kernel<<<(NNZ / 4 + 255) / 256, 256, 0, stream>>>(frows, fcols, fvals, Gb, F);
}

// Round 8
// 320.654 us; speedup vs baseline: 2.7907x; 1.0542x over previous
//
#include <hip/hip_runtime.h>
#include <math.h>

#define N_ATOMS 50000
#define IN_DIM 128
#define HID 256
#define N_ELEM 4
#define N_IMG 500
#define NNZ 2000000

typedef __attribute__((ext_vector_type(8))) short bf16x8;   // 8 bf16 = 4 VGPRs
typedef __attribute__((ext_vector_type(4))) float f32x4;    // MFMA C/D frag

__device__ __forceinline__ int elem_of(int z) {
    return (z == 1) ? 0 : (z == 6) ? 1 : (z == 8) ? 2 : 3;
}

__device__ __forceinline__ unsigned short f2bf(float f) {   // RNE
    unsigned u = __float_as_uint(f);
    u += 0x7fffu + ((u >> 16) & 1u);
    return (unsigned short)(u >> 16);
}
__device__ __forceinline__ float bf2f(unsigned short u) {
    return __uint_as_float(((unsigned)u) << 16);
}
__device__ __forceinline__ float tanh_fast(float x) {
    float e = __expf(2.f * x);
    return (e - 1.f) / (e + 1.f);
}

// ---------------------------------------------------------------------------
// 1) Bucket atoms by element — LDS-aggregated (4 global atomics per block).
// ---------------------------------------------------------------------------
__global__ __launch_bounds__(256) void bucket_kernel(
    const int* __restrict__ Z, int* __restrict__ counts, int* __restrict__ lists) {
    __shared__ int lcnt[N_ELEM], lbase[N_ELEM];
    const int i = blockIdx.x * blockDim.x + threadIdx.x;
    if (threadIdx.x < N_ELEM) lcnt[threadIdx.x] = 0;
    __syncthreads();
    int e = -1, pos = 0;
    if (i < N_ATOMS) {
        e = elem_of(Z[i]);
        pos = atomicAdd(&lcnt[e], 1);
    }
    __syncthreads();
    if (threadIdx.x < N_ELEM)
        lbase[threadIdx.x] = atomicAdd(&counts[threadIdx.x], lcnt[threadIdx.x]);
    __syncthreads();
    if (i < N_ATOMS) lists[e * N_ATOMS + lbase[e] + pos] = i;
}

// ---------------------------------------------------------------------------
// 1b) Weight prep (+ zero counts: runs before bucket, saves a memset dispatch).
//     bf16 plain ([e][k][n], B^T for backward) and transposed ([e][n][k]).
// ---------------------------------------------------------------------------
__global__ __launch_bounds__(256) void prep_weights(
    const float* __restrict__ W0, const float* __restrict__ W1,
    unsigned short* __restrict__ W0b, unsigned short* __restrict__ W0T,
    unsigned short* __restrict__ W1b, unsigned short* __restrict__ W1T,
    int* __restrict__ counts) {
    if (blockIdx.x == 0 && threadIdx.x < N_ELEM) counts[threadIdx.x] = 0;
    int t = blockIdx.x * 256 + threadIdx.x;
    if (t >= N_ELEM * HID * HID) return;
    int e = t >> 16;
    int rem = t & 65535;
    int k = rem >> 8, n = rem & 255;
    unsigned short w1 = f2bf(W1[t]);
    W1b[t] = w1;
    W1T[(e << 16) + (n << 8) + k] = w1;
    if (k < IN_DIM) {
        int i0 = e * (IN_DIM * HID) + rem;
        unsigned short w0 = f2bf(W0[i0]);
        W0b[i0] = w0;
        W0T[e * (IN_DIM * HID) + n * IN_DIM + k] = w0;
    }
}

// ---------------------------------------------------------------------------
// 2) FULLY-FUSED MLP fwd+bwd, R7 post-mortem redesign.
//    R7 was barrier/LDS-serialized: 28 K-iters x 2 barriers in 4-wave
//    lockstep, B round-tripping global->LDS->regs (MfmaUtil 6%). Fix: the
//    MFMA B-frag layout [n=lane&15][k=(lane>>4)*8+j] is DIRECTLY loadable
//    from B^T-row-major global memory (lane -> Bt + n*KD + lq*8, 16 B) — so
//    B skips LDS entirely and K-loops have NO barriers; weights stay
//    L2-resident across the ~1.5k blocks. Stage-1 A-frags are likewise
//    loaded straight from gathered fp rows (fp32->bf16 in regs). LDS holds
//    only the 32-row h0/dz1/dz0 tiles (chunk-major, stride 34 = 17-bank
//    rotation -> 2-way max, free per m136): 35 KB -> 4 blocks/CU, 16
//    waves/CU, 3 barriers per block total. B regs double-buffered.
//    Block = 256 thr = 4 waves, M=32 rows, wave n-range = 64 cols (NT=4).
//      S1: h0 = tanh(fp@W0T + b0)              -> tH
//      S2: t = tanh(h0@W1T + b1); o=sum t*W2   -> red/o_atom; dz1 -> tD
//      S3: dz0 = (dz1@W1b) * (1-h0^2)          -> tH (in-place, same thread)
//      S4: g = dz0@W0b                         -> tD -> coalesced Gb scatter
// ---------------------------------------------------------------------------
__global__ __launch_bounds__(256, 4) void fused_mlp(
    const float* __restrict__ fp,
    const unsigned short* __restrict__ W0T,   // [e][n=256][k=128]
    const unsigned short* __restrict__ W1T,   // [e][n=256][k=256]
    const unsigned short* __restrict__ W1b,   // [e][k=256][n=256] (plain W1)
    const unsigned short* __restrict__ W0b,   // [e][k=128][n=256] (plain W0)
    const float* __restrict__ b0, const float* __restrict__ b1,
    const float* __restrict__ W2, const float* __restrict__ b2,
    float* __restrict__ o_atom,
    unsigned short* __restrict__ Gb,
    const int* __restrict__ counts, const int* __restrict__ lists) {

    const int e = blockIdx.z;
    const int cnt = counts[e];
    const int m0 = blockIdx.x * 32;
    if (m0 >= cnt) return;
    const int* list = lists + e * N_ATOMS;

    // chunk-major tiles: chunk c (32 cols) at c*1088, row stride 34 shorts
    __shared__ short tH[8 * 32 * 34];      // 17408 B
    __shared__ short tD[8 * 32 * 34];      // 17408 B
    __shared__ float red[4][32];           // 512 B   (total 35328 B)

    const int tid = threadIdx.x;
    const int lane = tid & 63;
    const int wv = tid >> 6;       // 0..3, n-range wv*64
    const int lr = lane & 15;
    const int lq = lane >> 4;

    const unsigned short* W0Te = W0T + (size_t)e * HID * IN_DIM;
    const unsigned short* W1Te = W1T + (size_t)e * HID * HID;
    const unsigned short* W1be = W1b + (size_t)e * HID * HID;
    const unsigned short* W0be = W0b + (size_t)e * IN_DIM * HID;

    // A-row pointers for the 2 m-tiles (rows mt*16 + lr)
    const float* arow[2];
    bool aok[2];
#pragma unroll
    for (int mt = 0; mt < 2; ++mt) {
        int m = m0 + mt * 16 + lr;
        aok[mt] = (m < cnt);
        arow[mt] = aok[mt] ? (fp + (size_t)list[m] * IN_DIM) : fp;
    }

    f32x4 acc[2][4];
#define ZERO_ACC()                                                        \
    _Pragma("unroll") for (int mt = 0; mt < 2; ++mt)                      \
        _Pragma("unroll") for (int nt = 0; nt < 4; ++nt)                  \
            _Pragma("unroll") for (int j = 0; j < 4; ++j) acc[mt][nt][j] = 0.f;

    // =============== Stage 1: z0 = fp @ W0T   (K=128, 4 iters) =============
    ZERO_ACC();
#pragma unroll
    for (int ki = 0; ki < 4; ++ki) {
        const int k0 = ki * 32;
        bf16x8 af[2], bfr[4];
#pragma unroll
        for (int mt = 0; mt < 2; ++mt) {
            bf16x8 v;
#pragma unroll
            for (int j = 0; j < 8; ++j) v[j] = 0;
            if (aok[mt]) {
                float4 x = *(const float4*)(arow[mt] + k0 + lq * 8);
                float4 y = *(const float4*)(arow[mt] + k0 + lq * 8 + 4);
                v[0] = (short)f2bf(x.x); v[1] = (short)f2bf(x.y);
                v[2] = (short)f2bf(x.z); v[3] = (short)f2bf(x.w);
                v[4] = (short)f2bf(y.x); v[5] = (short)f2bf(y.y);
                v[6] = (short)f2bf(y.z); v[7] = (short)f2bf(y.w);
            }
            af[mt] = v;
        }
#pragma unroll
        for (int nt = 0; nt < 4; ++nt)
            bfr[nt] = *(const bf16x8*)(W0Te +
                (size_t)(wv * 64 + nt * 16 + lr) * IN_DIM + k0 + lq * 8);
#pragma unroll
        for (int mt = 0; mt < 2; ++mt)
#pragma unroll
            for (int nt = 0; nt < 4; ++nt)
                acc[mt][nt] = __builtin_amdgcn_mfma_f32_16x16x32_bf16(
                    af[mt], bfr[nt], acc[mt][nt], 0, 0, 0);
    }
    // epilogue 1: h0 -> tH
    {
        float bv[4];
#pragma unroll
        for (int nt = 0; nt < 4; ++nt)
            bv[nt] = b0[e * HID + wv * 64 + nt * 16 + lr];
#pragma unroll
        for (int mt = 0; mt < 2; ++mt)
#pragma unroll
            for (int r = 0; r < 4; ++r) {
                const int row = mt * 16 + lq * 4 + r;
#pragma unroll
                for (int nt = 0; nt < 4; ++nt) {
                    const int n = wv * 64 + nt * 16 + lr;
                    float t = tanh_fast(acc[mt][nt][r] + bv[nt]);
                    tH[(n >> 5) * 1088 + row * 34 + (n & 31)] = (short)f2bf(t);
                }
            }
    }
    __syncthreads();

    // =============== Stage 2: z1 = h0 @ W1T   (K=256, 8 iters) =============
    ZERO_ACC();
    {
        bf16x8 bc[4], bn[4];
#pragma unroll
        for (int nt = 0; nt < 4; ++nt)
            bc[nt] = *(const bf16x8*)(W1Te +
                (size_t)(wv * 64 + nt * 16 + lr) * HID + lq * 8);
#pragma unroll
        for (int ki = 0; ki < 8; ++ki) {
            if (ki < 7) {
                const int k0n = (ki + 1) * 32;
#pragma unroll
                for (int nt = 0; nt < 4; ++nt)
                    bn[nt] = *(const bf16x8*)(W1Te +
                        (size_t)(wv * 64 + nt * 16 + lr) * HID + k0n + lq * 8);
            }
            bf16x8 af[2];
#pragma unroll
            for (int mt = 0; mt < 2; ++mt)
                af[mt] = *(const bf16x8*)&tH[ki * 1088 + (mt * 16 + lr) * 34 + lq * 8];
#pragma unroll
            for (int mt = 0; mt < 2; ++mt)
#pragma unroll
                for (int nt = 0; nt < 4; ++nt)
                    acc[mt][nt] = __builtin_amdgcn_mfma_f32_16x16x32_bf16(
                        af[mt], bc[nt], acc[mt][nt], 0, 0, 0);
#pragma unroll
            for (int nt = 0; nt < 4; ++nt) bc[nt] = bn[nt];
        }
    }
    // epilogue 2: dz1 -> tD; o partials -> red
    {
        float bv[4], w2v[4];
#pragma unroll
        for (int nt = 0; nt < 4; ++nt) {
            bv[nt]  = b1[e * HID + wv * 64 + nt * 16 + lr];
            w2v[nt] = W2[e * HID + wv * 64 + nt * 16 + lr];
        }
#pragma unroll
        for (int mt = 0; mt < 2; ++mt)
#pragma unroll
            for (int r = 0; r < 4; ++r) {
                const int row = mt * 16 + lq * 4 + r;
                float osum = 0.f;
#pragma unroll
                for (int nt = 0; nt < 4; ++nt) {
                    const int n = wv * 64 + nt * 16 + lr;
                    float t = tanh_fast(acc[mt][nt][r] + bv[nt]);
                    osum += t * w2v[nt];
                    tD[(n >> 5) * 1088 + row * 34 + (n & 31)] =
                        (short)f2bf(w2v[nt] * (1.f - t * t));
                }
                osum += __shfl_xor(osum, 1, 64);
                osum += __shfl_xor(osum, 2, 64);
                osum += __shfl_xor(osum, 4, 64);
                osum += __shfl_xor(osum, 8, 64);
                if (lr == 0) red[wv][row] = osum;
            }
    }
    __syncthreads();
    if (tid < 32) {
        int m = m0 + tid;
        if (m < cnt)
            o_atom[list[m]] = red[0][tid] + red[1][tid] + red[2][tid] +
                              red[3][tid] + b2[e];
    }

    // =============== Stage 3: dh0 = dz1 @ W1b  (K=256, 8 iters) ============
    ZERO_ACC();
    {
        bf16x8 bc[4], bn[4];
#pragma unroll
        for (int nt = 0; nt < 4; ++nt)
            bc[nt] = *(const bf16x8*)(W1be +
                (size_t)(wv * 64 + nt * 16 + lr) * HID + lq * 8);
#pragma unroll
        for (int ki = 0; ki < 8; ++ki) {
            if (ki < 7) {
                const int k0n = (ki + 1) * 32;
#pragma unroll
                for (int nt = 0; nt < 4; ++nt)
                    bn[nt] = *(const bf16x8*)(W1be +
                        (size_t)(wv * 64 + nt * 16 + lr) * HID + k0n + lq * 8);
            }
            bf16x8 af[2];
#pragma unroll
            for (int mt = 0; mt < 2; ++mt)
                af[mt] = *(const bf16x8*)&tD[ki * 1088 + (mt * 16 + lr) * 34 + lq * 8];
#pragma unroll
            for (int mt = 0; mt < 2; ++mt)
#pragma unroll
                for (int nt = 0; nt < 4; ++nt)
                    acc[mt][nt] = __builtin_amdgcn_mfma_f32_16x16x32_bf16(
                        af[mt], bc[nt], acc[mt][nt], 0, 0, 0);
#pragma unroll
            for (int nt = 0; nt < 4; ++nt) bc[nt] = bn[nt];
        }
    }
    // epilogue 3: dz0 = dh0*(1-h0^2) -> tH in-place (same thread owns slot)
#pragma unroll
    for (int mt = 0; mt < 2; ++mt)
#pragma unroll
        for (int r = 0; r < 4; ++r) {
            const int row = mt * 16 + lq * 4 + r;
#pragma unroll
            for (int nt = 0; nt < 4; ++nt) {
                const int n = wv * 64 + nt * 16 + lr;
                const int a = (n >> 5) * 1088 + row * 34 + (n & 31);
                float h = bf2f((unsigned short)tH[a]);
                tH[a] = (short)f2bf(acc[mt][nt][r] * (1.f - h * h));
            }
        }
    __syncthreads();

    // =============== Stage 4: g = dz0 @ W0b   (K=256, N=128, NT=2) =========
    {
        f32x4 a4[2][2];
#pragma unroll
        for (int mt = 0; mt < 2; ++mt)
#pragma unroll
            for (int nt = 0; nt < 2; ++nt)
#pragma unroll
                for (int j = 0; j < 4; ++j) a4[mt][nt][j] = 0.f;
        bf16x8 bc[2], bn[2];
#pragma unroll
        for (int nt = 0; nt < 2; ++nt)
            bc[nt] = *(const bf16x8*)(W0be +
                (size_t)(wv * 32 + nt * 16 + lr) * HID + lq * 8);
#pragma unroll
        for (int ki = 0; ki < 8; ++ki) {
            if (ki < 7) {
                const int k0n = (ki + 1) * 32;
#pragma unroll
                for (int nt = 0; nt < 2; ++nt)
                    bn[nt] = *(const bf16x8*)(W0be +
                        (size_t)(wv * 32 + nt * 16 + lr) * HID + k0n + lq * 8);
            }
            bf16x8 af[2];
#pragma unroll
            for (int mt = 0; mt < 2; ++mt)
                af[mt] = *(const bf16x8*)&tH[ki * 1088 + (mt * 16 + lr) * 34 + lq * 8];
#pragma unroll
            for (int mt = 0; mt < 2; ++mt)
#pragma unroll
                for (int nt = 0; nt < 2; ++nt)
                    a4[mt][nt] = __builtin_amdgcn_mfma_f32_16x16x32_bf16(
                        af[mt], bc[nt], a4[mt][nt], 0, 0, 0);
#pragma unroll
            for (int nt = 0; nt < 2; ++nt) bc[nt] = bn[nt];
        }
        // epilogue 4: g -> tD chunk-major, then coalesced bf16x8 scatter
#pragma unroll
        for (int mt = 0; mt < 2; ++mt)
#pragma unroll
            for (int r = 0; r < 4; ++r) {
                const int row = mt * 16 + lq * 4 + r;
#pragma unroll
                for (int nt = 0; nt < 2; ++nt) {
                    const int n = wv * 32 + nt * 16 + lr;
                    tD[(n >> 5) * 1088 + row * 34 + (n & 31)] =
                        (short)f2bf(a4[mt][nt][r]);
                }
            }
    }
    __syncthreads();
#pragma unroll
    for (int t = 0; t < 2; ++t) {
        const int c = tid + 256 * t;         // 0..511
        const int row = c >> 4;              // 0..31
        const int pos = (c & 15) * 8;        // 0..120
        const int m = m0 + row;
        if (m < cnt) {
            bf16x8 v = *(const bf16x8*)&tD[(pos >> 5) * 1088 + row * 34 + (pos & 31)];
            *(bf16x8*)(Gb + (size_t)list[m] * IN_DIM + pos) = v;
        }
    }
#undef ZERO_ACC
}

// ---------------------------------------------------------------------------
// 3) Energy (+ zero F for the forces atomics — saves the d_out memset).
// ---------------------------------------------------------------------------
__global__ __launch_bounds__(256) void energy_kernel(
    const float* __restrict__ o_atom, const int* __restrict__ img,
    float* __restrict__ energy, float* __restrict__ F) {
    for (int idx = blockIdx.x * 256 + threadIdx.x; idx < 3 * N_ATOMS;
         idx += N_IMG * 256) F[idx] = 0.f;
    const int b = blockIdx.x;
    int lo, hi;
    {
        int l = 0, r = N_ATOMS;
        while (l < r) { int m = (l + r) >> 1; if (img[m] < b) l = m + 1; else r = m; }
        lo = l;
    }
    {
        int l = lo, r = N_ATOMS;
        while (l < r) { int m = (l + r) >> 1; if (img[m] < b + 1) l = m + 1; else r = m; }
        hi = l;
    }
    float s = 0.f;
    for (int i = lo + (int)threadIdx.x; i < hi; i += (int)blockDim.x) s += o_atom[i];
#pragma unroll
    for (int off = 32; off > 0; off >>= 1) s += __shfl_down(s, off, 64);
    __shared__ float red[4];
    if ((threadIdx.x & 63) == 0) red[threadIdx.x >> 6] = s;
    __syncthreads();
    if (threadIdx.x == 0) energy[b] = red[0] + red[1] + red[2] + red[3];
}

// ---------------------------------------------------------------------------
// 4) Forces — latency/atomic-throughput bound (~110us floor at this
//    structure). R6 shape kept: 4/thread, 1954 blocks, bf16 g.
// ---------------------------------------------------------------------------
__global__ __launch_bounds__(256) void forces_kernel(
    const int* __restrict__ rows, const int* __restrict__ cols,
    const float* __restrict__ vals, const unsigned short* __restrict__ g,
    float* __restrict__ F) {
    const int i0 = (blockIdx.x * 256 + threadIdx.x) * 4;
    if (i0 >= NNZ) return;
    int4 r = *(const int4*)(rows + i0);
    int4 c = *(const int4*)(cols + i0);
    float4 v = *(const float4*)(vals + i0);
    float g0 = bf2f(g[r.x]), g1 = bf2f(g[r.y]), g2 = bf2f(g[r.z]), g3 = bf2f(g[r.w]);
    atomicAdd(&F[c.x], -v.x * g0);
    atomicAdd(&F[c.y], -v.y * g1);
    atomicAdd(&F[c.z], -v.z * g2);
    atomicAdd(&F[c.w], -v.w * g3);
}

// ---------------------------------------------------------------------------
extern "C" void kernel_launch(void* const* d_in, const int* in_sizes, int n_in,
                              void* d_out, int out_size, void* d_ws, size_t ws_size,
                              hipStream_t stream) {
    const float* fp    = (const float*)d_in[0];
    const int*   Z     = (const int*)d_in[1];
    const int*   img   = (const int*)d_in[2];
    const int*   frows = (const int*)d_in[3];
    const int*   fcols = (const int*)d_in[4];
    const float* fvals = (const float*)d_in[5];
    const float* W0    = (const float*)d_in[6];
    const float* b0    = (const float*)d_in[7];
    const float* W1    = (const float*)d_in[8];
    const float* b1    = (const float*)d_in[9];
    const float* W2    = (const float*)d_in[10];
    const float* b2    = (const float*)d_in[11];

    float* out    = (float*)d_out;
    float* energy = out;             // [N_IMG]
    float* F      = out + N_IMG;     // [3*N_ATOMS]

    char* ws = (char*)d_ws;
    int*   counts = (int*)ws;                                   // 16 B
    int*   lists  = (int*)(ws + 1024);                          // 800 KB
    char*  base   = ws + (1 << 20);
    unsigned short* Gb   = (unsigned short*)(base);              // 50000*128 bf16 (atom order)
    float* o_atom        = (float*)(base + 13000000);            // 50000 f32
    unsigned short* W0b  = (unsigned short*)(base + 14000000);   // [e][k][n]
    unsigned short* W0T  = W0b + N_ELEM * IN_DIM * HID;          // [e][n][k]
    unsigned short* W1b  = W0T + N_ELEM * IN_DIM * HID;          // [e][k][n]
    unsigned short* W1T  = W1b + N_ELEM * HID * HID;             // [e][n][k]

    // 5 dispatches total (R7 post-mortem: ~90us unaccounted outside the two
    // big kernels — memsets folded into prep_weights / energy_kernel).
    prep_weights<<<(N_ELEM * HID * HID + 255) / 256, 256, 0, stream>>>(
        W0, W1, W0b, W0T, W1b, W1T, counts);
    bucket_kernel<<<(N_ATOMS + 255) / 256, 256, 0, stream>>>(Z, counts, lists);

    const int MT = (N_ATOMS + 31) / 32;   // 1563 x-tiles; ~391/element active
    fused_mlp<<<dim3(MT, 1, N_ELEM), 256, 0, stream>>>(
        fp, W0T, W1T, W1b, W0b, b0, b1, W2, b2, o_atom, Gb, counts, lists);

    energy_kernel<<<N_IMG, 256, 0, stream>>>(o_atom, img, energy, F);

    forces_kernel<<<(NNZ / 4 + 255) / 256, 256, 0, stream>>>(frows, fcols, fvals, Gb, F);
}

// Round 9
// 276.598 us; speedup vs baseline: 3.2351x; 1.1593x over previous
//
#include <hip/hip_runtime.h>
#include <math.h>

#define N_ATOMS 50000
#define IN_DIM 128
#define HID 256
#define N_ELEM 4
#define N_IMG 500
#define NNZ 2000000

typedef __attribute__((ext_vector_type(8))) short bf16x8;   // 8 bf16 = 4 VGPRs
typedef __attribute__((ext_vector_type(4))) float f32x4;    // MFMA C/D frag

__device__ __forceinline__ int elem_of(int z) {
    return (z == 1) ? 0 : (z == 6) ? 1 : (z == 8) ? 2 : 3;
}

__device__ __forceinline__ unsigned short f2bf(float f) {   // RNE
    unsigned u = __float_as_uint(f);
    u += 0x7fffu + ((u >> 16) & 1u);
    return (unsigned short)(u >> 16);
}
__device__ __forceinline__ float bf2f(unsigned short u) {
    return __uint_as_float(((unsigned)u) << 16);
}
__device__ __forceinline__ float tanh_fast(float x) {
    float e = __expf(2.f * x);
    return (e - 1.f) / (e + 1.f);
}

// ---------------------------------------------------------------------------
// 1) Bucket atoms by element — LDS-aggregated (4 global atomics per block).
// ---------------------------------------------------------------------------
__global__ __launch_bounds__(256) void bucket_kernel(
    const int* __restrict__ Z, int* __restrict__ counts, int* __restrict__ lists) {
    __shared__ int lcnt[N_ELEM], lbase[N_ELEM];
    const int i = blockIdx.x * blockDim.x + threadIdx.x;
    if (threadIdx.x < N_ELEM) lcnt[threadIdx.x] = 0;
    __syncthreads();
    int e = -1, pos = 0;
    if (i < N_ATOMS) {
        e = elem_of(Z[i]);
        pos = atomicAdd(&lcnt[e], 1);
    }
    __syncthreads();
    if (threadIdx.x < N_ELEM)
        lbase[threadIdx.x] = atomicAdd(&counts[threadIdx.x], lcnt[threadIdx.x]);
    __syncthreads();
    if (i < N_ATOMS) lists[e * N_ATOMS + lbase[e] + pos] = i;
}

// ---------------------------------------------------------------------------
// 1b) Weight prep — R8 post-mortem: direct-from-global B-frags were
//     UNCOALESCED (16 rows x stride-512B per wave load -> ~64 scattered 16-B
//     requests, transaction-bound like forces). Fix: pre-swizzle every weight
//     matrix into wave-frag order [(ntile16*KN + kchunk32)][lane][8] so one
//     frag load = 64 lanes x contiguous 16 B = one 1-KB coalesced block.
//     For Bt[N][K] and element (n,k): lane = ((k>>3)&3)<<4 | (n&15),
//     idx = (((n>>4)*KN + (k>>5))*64 + lane)*8 + (k&7).
//     Four swizzled copies: S1 Bt=W0^T, S2 Bt=W1^T, S3 Bt=W1, S4 Bt=W0.
//     Also zeroes counts (block 0) — saves a memset dispatch.
// ---------------------------------------------------------------------------
__global__ __launch_bounds__(256) void prep_weights(
    const float* __restrict__ W0, const float* __restrict__ W1,
    unsigned short* __restrict__ W0s1,   // stage1: Bt[h][d], K=128, KN=4
    unsigned short* __restrict__ W1s2,   // stage2: Bt[h1][h0], K=256, KN=8
    unsigned short* __restrict__ W1s3,   // stage3: Bt[h0][h1], K=256, KN=8
    unsigned short* __restrict__ W0s4,   // stage4: Bt[d][h], K=256, KN=8
    int* __restrict__ counts) {
    if (blockIdx.x == 0 && threadIdx.x < N_ELEM) counts[threadIdx.x] = 0;
    int t = blockIdx.x * 256 + threadIdx.x;
    if (t >= N_ELEM * HID * HID) return;
    int e = t >> 16;
    int rem = t & 65535;
    int k = rem >> 8, n = rem & 255;     // W1[e][k=h0][n=h1]
    unsigned short w1 = f2bf(W1[t]);
    {   // stage2: row = n (h1), col = k (h0)
        int lane = (((k >> 3) & 3) << 4) | (n & 15);
        W1s2[(e << 16) + ((((n >> 4) * 8 + (k >> 5)) * 64 + lane) << 3) + (k & 7)] = w1;
    }
    {   // stage3: row = k (h0), col = n (h1)
        int lane = (((n >> 3) & 3) << 4) | (k & 15);
        W1s3[(e << 16) + ((((k >> 4) * 8 + (n >> 5)) * 64 + lane) << 3) + (n & 7)] = w1;
    }
    if (k < IN_DIM) {                    // W0[e][d=k][h=n]
        unsigned short w0 = f2bf(W0[e * (IN_DIM * HID) + rem]);
        {   // stage1: row = n (h), col = k (d), K=128 -> KN=4
            int lane = (((k >> 3) & 3) << 4) | (n & 15);
            W0s1[e * (IN_DIM * HID) + ((((n >> 4) * 4 + (k >> 5)) * 64 + lane) << 3) + (k & 7)] = w0;
        }
        {   // stage4: row = k (d), col = n (h), K=256 -> KN=8
            int lane = (((n >> 3) & 3) << 4) | (k & 15);
            W0s4[e * (IN_DIM * HID) + ((((k >> 4) * 8 + (n >> 5)) * 64 + lane) << 3) + (n & 7)] = w0;
        }
    }
}

// ---------------------------------------------------------------------------
// 2) FULLY-FUSED MLP fwd+bwd (R8 structure + swizzled coalesced B loads).
//    Barrier-free K-loops: B-frags stream straight from the swizzled global
//    arrays (1-KB coalesced wave loads, L2-resident); LDS holds only the
//    32-row h0/dz1/dz0 chunk-major tiles (stride 34 -> 2-way max, free).
//    35 KB LDS -> 4 blocks/CU. B regs double-buffered across K.
//      S1: h0 = tanh(fp@W0^T + b0)             -> tH
//      S2: t = tanh(h0@W1^T + b1); o=sum t*W2  -> red/o_atom; dz1 -> tD
//      S3: dz0 = (dz1@W1) * (1-h0^2)           -> tH (in-place, same thread)
//      S4: g = dz0@W0                          -> tD -> coalesced Gb scatter
// ---------------------------------------------------------------------------
__global__ __launch_bounds__(256, 4) void fused_mlp(
    const float* __restrict__ fp,
    const unsigned short* __restrict__ W0s1,
    const unsigned short* __restrict__ W1s2,
    const unsigned short* __restrict__ W1s3,
    const unsigned short* __restrict__ W0s4,
    const float* __restrict__ b0, const float* __restrict__ b1,
    const float* __restrict__ W2, const float* __restrict__ b2,
    float* __restrict__ o_atom,
    unsigned short* __restrict__ Gb,
    const int* __restrict__ counts, const int* __restrict__ lists) {

    const int e = blockIdx.z;
    const int cnt = counts[e];
    const int m0 = blockIdx.x * 32;
    if (m0 >= cnt) return;
    const int* list = lists + e * N_ATOMS;

    __shared__ short tH[8 * 32 * 34];      // 17408 B
    __shared__ short tD[8 * 32 * 34];      // 17408 B
    __shared__ float red[4][32];           // 512 B   (total 35328 B)

    const int tid = threadIdx.x;
    const int lane = tid & 63;
    const int wv = tid >> 6;       // 0..3, n-range wv*64
    const int lr = lane & 15;
    const int lq = lane >> 4;

    const unsigned short* B1 = W0s1 + (size_t)e * HID * IN_DIM;
    const unsigned short* B2 = W1s2 + (size_t)e * HID * HID;
    const unsigned short* B3 = W1s3 + (size_t)e * HID * HID;
    const unsigned short* B4 = W0s4 + (size_t)e * IN_DIM * HID;

    // A-row pointers for the 2 m-tiles (rows mt*16 + lr)
    const float* arow[2];
    bool aok[2];
#pragma unroll
    for (int mt = 0; mt < 2; ++mt) {
        int m = m0 + mt * 16 + lr;
        aok[mt] = (m < cnt);
        arow[mt] = aok[mt] ? (fp + (size_t)list[m] * IN_DIM) : fp;
    }

    f32x4 acc[2][4];
#define ZERO_ACC()                                                        \
    _Pragma("unroll") for (int mt = 0; mt < 2; ++mt)                      \
        _Pragma("unroll") for (int nt = 0; nt < 4; ++nt)                  \
            _Pragma("unroll") for (int j = 0; j < 4; ++j) acc[mt][nt][j] = 0.f;

    // =============== Stage 1: z0 = fp @ W0^T   (K=128, KN=4) ===============
    ZERO_ACC();
#pragma unroll
    for (int ki = 0; ki < 4; ++ki) {
        const int k0 = ki * 32;
        bf16x8 af[2], bfr[4];
#pragma unroll
        for (int mt = 0; mt < 2; ++mt) {
            bf16x8 v;
#pragma unroll
            for (int j = 0; j < 8; ++j) v[j] = 0;
            if (aok[mt]) {
                float4 x = *(const float4*)(arow[mt] + k0 + lq * 8);
                float4 y = *(const float4*)(arow[mt] + k0 + lq * 8 + 4);
                v[0] = (short)f2bf(x.x); v[1] = (short)f2bf(x.y);
                v[2] = (short)f2bf(x.z); v[3] = (short)f2bf(x.w);
                v[4] = (short)f2bf(y.x); v[5] = (short)f2bf(y.y);
                v[6] = (short)f2bf(y.z); v[7] = (short)f2bf(y.w);
            }
            af[mt] = v;
        }
#pragma unroll
        for (int nt = 0; nt < 4; ++nt)
            bfr[nt] = *(const bf16x8*)(B1 +
                ((size_t)(((wv * 4 + nt) * 4 + ki) * 64 + lane) << 3));
#pragma unroll
        for (int mt = 0; mt < 2; ++mt)
#pragma unroll
            for (int nt = 0; nt < 4; ++nt)
                acc[mt][nt] = __builtin_amdgcn_mfma_f32_16x16x32_bf16(
                    af[mt], bfr[nt], acc[mt][nt], 0, 0, 0);
    }
    // epilogue 1: h0 -> tH
    {
        float bv[4];
#pragma unroll
        for (int nt = 0; nt < 4; ++nt)
            bv[nt] = b0[e * HID + wv * 64 + nt * 16 + lr];
#pragma unroll
        for (int mt = 0; mt < 2; ++mt)
#pragma unroll
            for (int r = 0; r < 4; ++r) {
                const int row = mt * 16 + lq * 4 + r;
#pragma unroll
                for (int nt = 0; nt < 4; ++nt) {
                    const int n = wv * 64 + nt * 16 + lr;
                    float t = tanh_fast(acc[mt][nt][r] + bv[nt]);
                    tH[(n >> 5) * 1088 + row * 34 + (n & 31)] = (short)f2bf(t);
                }
            }
    }
    __syncthreads();

    // =============== Stage 2: z1 = h0 @ W1^T   (K=256, KN=8) ===============
    ZERO_ACC();
    {
        bf16x8 bc[4], bn[4];
#pragma unroll
        for (int nt = 0; nt < 4; ++nt)
            bc[nt] = *(const bf16x8*)(B2 +
                ((size_t)(((wv * 4 + nt) * 8 + 0) * 64 + lane) << 3));
#pragma unroll
        for (int ki = 0; ki < 8; ++ki) {
            if (ki < 7) {
#pragma unroll
                for (int nt = 0; nt < 4; ++nt)
                    bn[nt] = *(const bf16x8*)(B2 +
                        ((size_t)(((wv * 4 + nt) * 8 + ki + 1) * 64 + lane) << 3));
            }
            bf16x8 af[2];
#pragma unroll
            for (int mt = 0; mt < 2; ++mt)
                af[mt] = *(const bf16x8*)&tH[ki * 1088 + (mt * 16 + lr) * 34 + lq * 8];
#pragma unroll
            for (int mt = 0; mt < 2; ++mt)
#pragma unroll
                for (int nt = 0; nt < 4; ++nt)
                    acc[mt][nt] = __builtin_amdgcn_mfma_f32_16x16x32_bf16(
                        af[mt], bc[nt], acc[mt][nt], 0, 0, 0);
#pragma unroll
            for (int nt = 0; nt < 4; ++nt) bc[nt] = bn[nt];
        }
    }
    // epilogue 2: dz1 -> tD; o partials -> red
    {
        float bv[4], w2v[4];
#pragma unroll
        for (int nt = 0; nt < 4; ++nt) {
            bv[nt]  = b1[e * HID + wv * 64 + nt * 16 + lr];
            w2v[nt] = W2[e * HID + wv * 64 + nt * 16 + lr];
        }
#pragma unroll
        for (int mt = 0; mt < 2; ++mt)
#pragma unroll
            for (int r = 0; r < 4; ++r) {
                const int row = mt * 16 + lq * 4 + r;
                float osum = 0.f;
#pragma unroll
                for (int nt = 0; nt < 4; ++nt) {
                    const int n = wv * 64 + nt * 16 + lr;
                    float t = tanh_fast(acc[mt][nt][r] + bv[nt]);
                    osum += t * w2v[nt];
                    tD[(n >> 5) * 1088 + row * 34 + (n & 31)] =
                        (short)f2bf(w2v[nt] * (1.f - t * t));
                }
                osum += __shfl_xor(osum, 1, 64);
                osum += __shfl_xor(osum, 2, 64);
                osum += __shfl_xor(osum, 4, 64);
                osum += __shfl_xor(osum, 8, 64);
                if (lr == 0) red[wv][row] = osum;
            }
    }
    __syncthreads();
    if (tid < 32) {
        int m = m0 + tid;
        if (m < cnt)
            o_atom[list[m]] = red[0][tid] + red[1][tid] + red[2][tid] +
                              red[3][tid] + b2[e];
    }

    // =============== Stage 3: dh0 = dz1 @ W1   (K=256, KN=8) ===============
    ZERO_ACC();
    {
        bf16x8 bc[4], bn[4];
#pragma unroll
        for (int nt = 0; nt < 4; ++nt)
            bc[nt] = *(const bf16x8*)(B3 +
                ((size_t)(((wv * 4 + nt) * 8 + 0) * 64 + lane) << 3));
#pragma unroll
        for (int ki = 0; ki < 8; ++ki) {
            if (ki < 7) {
#pragma unroll
                for (int nt = 0; nt < 4; ++nt)
                    bn[nt] = *(const bf16x8*)(B3 +
                        ((size_t)(((wv * 4 + nt) * 8 + ki + 1) * 64 + lane) << 3));
            }
            bf16x8 af[2];
#pragma unroll
            for (int mt = 0; mt < 2; ++mt)
                af[mt] = *(const bf16x8*)&tD[ki * 1088 + (mt * 16 + lr) * 34 + lq * 8];
#pragma unroll
            for (int mt = 0; mt < 2; ++mt)
#pragma unroll
                for (int nt = 0; nt < 4; ++nt)
                    acc[mt][nt] = __builtin_amdgcn_mfma_f32_16x16x32_bf16(
                        af[mt], bc[nt], acc[mt][nt], 0, 0, 0);
#pragma unroll
            for (int nt = 0; nt < 4; ++nt) bc[nt] = bn[nt];
        }
    }
    // epilogue 3: dz0 = dh0*(1-h0^2) -> tH in-place (same thread owns slot)
#pragma unroll
    for (int mt = 0; mt < 2; ++mt)
#pragma unroll
        for (int r = 0; r < 4; ++r) {
            const int row = mt * 16 + lq * 4 + r;
#pragma unroll
            for (int nt = 0; nt < 4; ++nt) {
                const int n = wv * 64 + nt * 16 + lr;
                const int a = (n >> 5) * 1088 + row * 34 + (n & 31);
                float h = bf2f((unsigned short)tH[a]);
                tH[a] = (short)f2bf(acc[mt][nt][r] * (1.f - h * h));
            }
        }
    __syncthreads();

    // =============== Stage 4: g = dz0 @ W0   (K=256, N=128, NT=2) ==========
    {
        f32x4 a4[2][2];
#pragma unroll
        for (int mt = 0; mt < 2; ++mt)
#pragma unroll
            for (int nt = 0; nt < 2; ++nt)
#pragma unroll
                for (int j = 0; j < 4; ++j) a4[mt][nt][j] = 0.f;
        bf16x8 bc[2], bn[2];
#pragma unroll
        for (int nt = 0; nt < 2; ++nt)
            bc[nt] = *(const bf16x8*)(B4 +
                ((size_t)(((wv * 2 + nt) * 8 + 0) * 64 + lane) << 3));
#pragma unroll
        for (int ki = 0; ki < 8; ++ki) {
            if (ki < 7) {
#pragma unroll
                for (int nt = 0; nt < 2; ++nt)
                    bn[nt] = *(const bf16x8*)(B4 +
                        ((size_t)(((wv * 2 + nt) * 8 + ki + 1) * 64 + lane) << 3));
            }
            bf16x8 af[2];
#pragma unroll
            for (int mt = 0; mt < 2; ++mt)
                af[mt] = *(const bf16x8*)&tH[ki * 1088 + (mt * 16 + lr) * 34 + lq * 8];
#pragma unroll
            for (int mt = 0; mt < 2; ++mt)
#pragma unroll
                for (int nt = 0; nt < 2; ++nt)
                    a4[mt][nt] = __builtin_amdgcn_mfma_f32_16x16x32_bf16(
                        af[mt], bc[nt], a4[mt][nt], 0, 0, 0);
#pragma unroll
            for (int nt = 0; nt < 2; ++nt) bc[nt] = bn[nt];
        }
        // epilogue 4: g -> tD chunk-major, then coalesced bf16x8 scatter
#pragma unroll
        for (int mt = 0; mt < 2; ++mt)
#pragma unroll
            for (int r = 0; r < 4; ++r) {
                const int row = mt * 16 + lq * 4 + r;
#pragma unroll
                for (int nt = 0; nt < 2; ++nt) {
                    const int n = wv * 32 + nt * 16 + lr;
                    tD[(n >> 5) * 1088 + row * 34 + (n & 31)] =
                        (short)f2bf(a4[mt][nt][r]);
                }
            }
    }
    __syncthreads();
#pragma unroll
    for (int t = 0; t < 2; ++t) {
        const int c = tid + 256 * t;         // 0..511
        const int row = c >> 4;              // 0..31
        const int pos = (c & 15) * 8;        // 0..120
        const int m = m0 + row;
        if (m < cnt) {
            bf16x8 v = *(const bf16x8*)&tD[(pos >> 5) * 1088 + row * 34 + (pos & 31)];
            *(bf16x8*)(Gb + (size_t)list[m] * IN_DIM + pos) = v;
        }
    }
#undef ZERO_ACC
}

// ---------------------------------------------------------------------------
// 3) Energy (+ zero F for the forces atomics — saves the d_out memset).
// ---------------------------------------------------------------------------
__global__ __launch_bounds__(256) void energy_kernel(
    const float* __restrict__ o_atom, const int* __restrict__ img,
    float* __restrict__ energy, float* __restrict__ F) {
    for (int idx = blockIdx.x * 256 + threadIdx.x; idx < 3 * N_ATOMS;
         idx += N_IMG * 256) F[idx] = 0.f;
    const int b = blockIdx.x;
    int lo, hi;
    {
        int l = 0, r = N_ATOMS;
        while (l < r) { int m = (l + r) >> 1; if (img[m] < b) l = m + 1; else r = m; }
        lo = l;
    }
    {
        int l = lo, r = N_ATOMS;
        while (l < r) { int m = (l + r) >> 1; if (img[m] < b + 1) l = m + 1; else r = m; }
        hi = l;
    }
    float s = 0.f;
    for (int i = lo + (int)threadIdx.x; i < hi; i += (int)blockDim.x) s += o_atom[i];
#pragma unroll
    for (int off = 32; off > 0; off >>= 1) s += __shfl_down(s, off, 64);
    __shared__ float red[4];
    if ((threadIdx.x & 63) == 0) red[threadIdx.x >> 6] = s;
    __syncthreads();
    if (threadIdx.x == 0) energy[b] = red[0] + red[1] + red[2] + red[3];
}

// ---------------------------------------------------------------------------
// 4) Forces — transaction-throughput bound (~110us: 2M random gathers + 2M
//    device-scope atomics ~= 4M fabric transactions). R6 shape kept.
// ---------------------------------------------------------------------------
__global__ __launch_bounds__(256) void forces_kernel(
    const int* __restrict__ rows, const int* __restrict__ cols,
    const float* __restrict__ vals, const unsigned short* __restrict__ g,
    float* __restrict__ F) {
    const int i0 = (blockIdx.x * 256 + threadIdx.x) * 4;
    if (i0 >= NNZ) return;
    int4 r = *(const int4*)(rows + i0);
    int4 c = *(const int4*)(cols + i0);
    float4 v = *(const float4*)(vals + i0);
    float g0 = bf2f(g[r.x]), g1 = bf2f(g[r.y]), g2 = bf2f(g[r.z]), g3 = bf2f(g[r.w]);
    atomicAdd(&F[c.x], -v.x * g0);
    atomicAdd(&F[c.y], -v.y * g1);
    atomicAdd(&F[c.z], -v.z * g2);
    atomicAdd(&F[c.w], -v.w * g3);
}

// ---------------------------------------------------------------------------
extern "C" void kernel_launch(void* const* d_in, const int* in_sizes, int n_in,
                              void* d_out, int out_size, void* d_ws, size_t ws_size,
                              hipStream_t stream) {
    const float* fp    = (const float*)d_in[0];
    const int*   Z     = (const int*)d_in[1];
    const int*   img   = (const int*)d_in[2];
    const int*   frows = (const int*)d_in[3];
    const int*   fcols = (const int*)d_in[4];
    const float* fvals = (const float*)d_in[5];
    const float* W0    = (const float*)d_in[6];
    const float* b0    = (const float*)d_in[7];
    const float* W1    = (const float*)d_in[8];
    const float* b1    = (const float*)d_in[9];
    const float* W2    = (const float*)d_in[10];
    const float* b2    = (const float*)d_in[11];

    float* out    = (float*)d_out;
    float* energy = out;             // [N_IMG]
    float* F      = out + N_IMG;     // [3*N_ATOMS]

    char* ws = (char*)d_ws;
    int*   counts = (int*)ws;                                   // 16 B
    int*   lists  = (int*)(ws + 1024);                          // 800 KB
    char*  base   = ws + (1 << 20);
    unsigned short* Gb   = (unsigned short*)(base);              // 50000*128 bf16 (atom order)
    float* o_atom        = (float*)(base + 13000000);            // 50000 f32
    unsigned short* W0s1 = (unsigned short*)(base + 14000000);   // swizzled, 256 KB
    unsigned short* W0s4 = W0s1 + N_ELEM * IN_DIM * HID;         // swizzled, 256 KB
    unsigned short* W1s2 = W0s4 + N_ELEM * IN_DIM * HID;         // swizzled, 512 KB
    unsigned short* W1s3 = W1s2 + N_ELEM * HID * HID;            // swizzled, 512 KB

    prep_weights<<<(N_ELEM * HID * HID + 255) / 256, 256, 0, stream>>>(
        W0, W1, W0s1, W1s2, W1s3, W0s4, counts);
    bucket_kernel<<<(N_ATOMS + 255) / 256, 256, 0, stream>>>(Z, counts, lists);

    const int MT = (N_ATOMS + 31) / 32;   // 1563 x-tiles; ~391/element active
    fused_mlp<<<dim3(MT, 1, N_ELEM), 256, 0, stream>>>(
        fp, W0s1, W1s2, W1s3, W0s4, b0, b1, W2, b2, o_atom, Gb, counts, lists);

    energy_kernel<<<N_IMG, 256, 0, stream>>>(o_atom, img, energy, F);

    forces_kernel<<<(NNZ / 4 + 255) / 256, 256, 0, stream>>>(frows, fcols, fvals, Gb, F);
}

// Round 10
// 273.777 us; speedup vs baseline: 3.2685x; 1.0103x over previous
//
#include <hip/hip_runtime.h>
#include <math.h>

#define N_ATOMS 50000
#define IN_DIM 128
#define HID 256
#define N_ELEM 4
#define N_IMG 500
#define NNZ 2000000

typedef __attribute__((ext_vector_type(8))) short bf16x8;   // 8 bf16 = 4 VGPRs
typedef __attribute__((ext_vector_type(4))) float f32x4;    // MFMA C/D frag

__device__ __forceinline__ int elem_of(int z) {
    return (z == 1) ? 0 : (z == 6) ? 1 : (z == 8) ? 2 : 3;
}

__device__ __forceinline__ unsigned short f2bf(float f) {   // RNE
    unsigned u = __float_as_uint(f);
    u += 0x7fffu + ((u >> 16) & 1u);
    return (unsigned short)(u >> 16);
}
__device__ __forceinline__ float bf2f(unsigned short u) {
    return __uint_as_float(((unsigned)u) << 16);
}
__device__ __forceinline__ float tanh_fast(float x) {
    float e = __expf(2.f * x);
    return (e - 1.f) / (e + 1.f);
}

// ---------------------------------------------------------------------------
// 1) Bucket atoms by element — LDS-aggregated. Also zeroes F (the forces
//    accumulator in d_out, poisoned 0xAA each call) — saves a dispatch.
// ---------------------------------------------------------------------------
__global__ __launch_bounds__(256) void bucket_kernel(
    const int* __restrict__ Z, int* __restrict__ counts, int* __restrict__ lists,
    float* __restrict__ F) {
    for (int idx = blockIdx.x * blockDim.x + threadIdx.x; idx < 3 * N_ATOMS;
         idx += gridDim.x * blockDim.x) F[idx] = 0.f;
    __shared__ int lcnt[N_ELEM], lbase[N_ELEM];
    const int i = blockIdx.x * blockDim.x + threadIdx.x;
    if (threadIdx.x < N_ELEM) lcnt[threadIdx.x] = 0;
    __syncthreads();
    int e = -1, pos = 0;
    if (i < N_ATOMS) {
        e = elem_of(Z[i]);
        pos = atomicAdd(&lcnt[e], 1);
    }
    __syncthreads();
    if (threadIdx.x < N_ELEM)
        lbase[threadIdx.x] = atomicAdd(&counts[threadIdx.x], lcnt[threadIdx.x]);
    __syncthreads();
    if (i < N_ATOMS) lists[e * N_ATOMS + lbase[e] + pos] = i;
}

// ---------------------------------------------------------------------------
// 1b) Weight prep — pre-swizzle weights into wave-frag order
//     [(ntile16*KN + kchunk32)][lane][8]: one frag load = 64 lanes x 16 B
//     contiguous = one coalesced 1-KB block (R9: this was worth 44us).
//     Also zeroes counts (block 0).
// ---------------------------------------------------------------------------
__global__ __launch_bounds__(256) void prep_weights(
    const float* __restrict__ W0, const float* __restrict__ W1,
    unsigned short* __restrict__ W0s1,   // stage1: Bt[h][d], K=128, KN=4
    unsigned short* __restrict__ W1s2,   // stage2: Bt[h1][h0], K=256, KN=8
    unsigned short* __restrict__ W1s3,   // stage3: Bt[h0][h1], K=256, KN=8
    unsigned short* __restrict__ W0s4,   // stage4: Bt[d][h], K=256, KN=8
    int* __restrict__ counts) {
    if (blockIdx.x == 0 && threadIdx.x < N_ELEM) counts[threadIdx.x] = 0;
    int t = blockIdx.x * 256 + threadIdx.x;
    if (t >= N_ELEM * HID * HID) return;
    int e = t >> 16;
    int rem = t & 65535;
    int k = rem >> 8, n = rem & 255;     // W1[e][k=h0][n=h1]
    unsigned short w1 = f2bf(W1[t]);
    {   // stage2: row = n (h1), col = k (h0)
        int lane = (((k >> 3) & 3) << 4) | (n & 15);
        W1s2[(e << 16) + ((((n >> 4) * 8 + (k >> 5)) * 64 + lane) << 3) + (k & 7)] = w1;
    }
    {   // stage3: row = k (h0), col = n (h1)
        int lane = (((n >> 3) & 3) << 4) | (k & 15);
        W1s3[(e << 16) + ((((k >> 4) * 8 + (n >> 5)) * 64 + lane) << 3) + (n & 7)] = w1;
    }
    if (k < IN_DIM) {                    // W0[e][d=k][h=n]
        unsigned short w0 = f2bf(W0[e * (IN_DIM * HID) + rem]);
        {   // stage1: row = n (h), col = k (d), K=128 -> KN=4
            int lane = (((k >> 3) & 3) << 4) | (n & 15);
            W0s1[e * (IN_DIM * HID) + ((((n >> 4) * 4 + (k >> 5)) * 64 + lane) << 3) + (k & 7)] = w0;
        }
        {   // stage4: row = k (d), col = n (h), K=256 -> KN=8
            int lane = (((n >> 3) & 3) << 4) | (k & 15);
            W0s4[e * (IN_DIM * HID) + ((((k >> 4) * 8 + (n >> 5)) * 64 + lane) << 3) + (n & 7)] = w0;
        }
    }
}

// ---------------------------------------------------------------------------
// 2) FULLY-FUSED MLP fwd+bwd. R9 post-mortem: B-stream is L2-resident but
//    latency-exposed — double-buffer lookahead (~70 cyc) << L2 latency
//    (~200-300 cyc). This round: ring-3 B prefetch in S2/S3/S4 (fully
//    unrolled -> constant indices, register-resident), ring-2 A+B in S1,
//    and each stage's initial prefetches hoisted ABOVE the preceding
//    epilogue + barrier so they fly during tanh VALU + barrier drain.
//    Barrier-free K-loops otherwise unchanged; LDS 35 KB -> 4 blocks/CU.
//      S1: h0 = tanh(fp@W0^T + b0)             -> tH
//      S2: t = tanh(h0@W1^T + b1); o=sum t*W2  -> red/o_atom; dz1 -> tD
//      S3: dz0 = (dz1@W1) * (1-h0^2)           -> tH (in-place, same thread)
//      S4: g = dz0@W0                          -> tD -> coalesced Gb scatter
// ---------------------------------------------------------------------------
__global__ __launch_bounds__(256, 4) void fused_mlp(
    const float* __restrict__ fp,
    const unsigned short* __restrict__ W0s1,
    const unsigned short* __restrict__ W1s2,
    const unsigned short* __restrict__ W1s3,
    const unsigned short* __restrict__ W0s4,
    const float* __restrict__ b0, const float* __restrict__ b1,
    const float* __restrict__ W2, const float* __restrict__ b2,
    float* __restrict__ o_atom,
    unsigned short* __restrict__ Gb,
    const int* __restrict__ counts, const int* __restrict__ lists) {

    const int e = blockIdx.z;
    const int cnt = counts[e];
    const int m0 = blockIdx.x * 32;
    if (m0 >= cnt) return;
    const int* list = lists + e * N_ATOMS;

    __shared__ short tH[8 * 32 * 34];      // 17408 B
    __shared__ short tD[8 * 32 * 34];      // 17408 B
    __shared__ float red[4][32];           // 512 B   (total 35328 B)

    const int tid = threadIdx.x;
    const int lane = tid & 63;
    const int wv = tid >> 6;       // 0..3, n-range wv*64
    const int lr = lane & 15;
    const int lq = lane >> 4;

    const unsigned short* B1 = W0s1 + (size_t)e * HID * IN_DIM;
    const unsigned short* B2 = W1s2 + (size_t)e * HID * HID;
    const unsigned short* B3 = W1s3 + (size_t)e * HID * HID;
    const unsigned short* B4 = W0s4 + (size_t)e * IN_DIM * HID;

    // A-row pointers for the 2 m-tiles (rows mt*16 + lr)
    const float* arow[2];
    bool aok[2];
#pragma unroll
    for (int mt = 0; mt < 2; ++mt) {
        int m = m0 + mt * 16 + lr;
        aok[mt] = (m < cnt);
        arow[mt] = aok[mt] ? (fp + (size_t)list[m] * IN_DIM) : fp;
    }

    f32x4 acc[2][4];
#define ZERO_ACC()                                                        \
    _Pragma("unroll") for (int mt = 0; mt < 2; ++mt)                      \
        _Pragma("unroll") for (int nt = 0; nt < 4; ++nt)                  \
            _Pragma("unroll") for (int j = 0; j < 4; ++j) acc[mt][nt][j] = 0.f;

    // =============== Stage 1: z0 = fp @ W0^T   (K=128, KN=4, ring-2) ======
    ZERO_ACC();
    {
        float4 a0[2][2], a1[2][2];
        bf16x8 bb[2][4];
#pragma unroll
        for (int mt = 0; mt < 2; ++mt) if (aok[mt]) {
            a0[0][mt] = *(const float4*)(arow[mt] + lq * 8);
            a1[0][mt] = *(const float4*)(arow[mt] + lq * 8 + 4);
        }
#pragma unroll
        for (int nt = 0; nt < 4; ++nt)
            bb[0][nt] = *(const bf16x8*)(B1 +
                ((size_t)(((wv * 4 + nt) * 4 + 0) * 64 + lane) << 3));
#pragma unroll
        for (int ki = 0; ki < 4; ++ki) {
            const int cur = ki & 1, nx = cur ^ 1;
            if (ki < 3) {
                const int k0n = (ki + 1) * 32;
#pragma unroll
                for (int mt = 0; mt < 2; ++mt) if (aok[mt]) {
                    a0[nx][mt] = *(const float4*)(arow[mt] + k0n + lq * 8);
                    a1[nx][mt] = *(const float4*)(arow[mt] + k0n + lq * 8 + 4);
                }
#pragma unroll
                for (int nt = 0; nt < 4; ++nt)
                    bb[nx][nt] = *(const bf16x8*)(B1 +
                        ((size_t)(((wv * 4 + nt) * 4 + ki + 1) * 64 + lane) << 3));
            }
            bf16x8 af[2];
#pragma unroll
            for (int mt = 0; mt < 2; ++mt) {
                bf16x8 v;
#pragma unroll
                for (int j = 0; j < 8; ++j) v[j] = 0;
                if (aok[mt]) {
                    v[0] = (short)f2bf(a0[cur][mt].x); v[1] = (short)f2bf(a0[cur][mt].y);
                    v[2] = (short)f2bf(a0[cur][mt].z); v[3] = (short)f2bf(a0[cur][mt].w);
                    v[4] = (short)f2bf(a1[cur][mt].x); v[5] = (short)f2bf(a1[cur][mt].y);
                    v[6] = (short)f2bf(a1[cur][mt].z); v[7] = (short)f2bf(a1[cur][mt].w);
                }
                af[mt] = v;
            }
#pragma unroll
            for (int mt = 0; mt < 2; ++mt)
#pragma unroll
                for (int nt = 0; nt < 4; ++nt)
                    acc[mt][nt] = __builtin_amdgcn_mfma_f32_16x16x32_bf16(
                        af[mt], bb[cur][nt], acc[mt][nt], 0, 0, 0);
        }
    }

    // S2 B-ring preload (hoisted: flies during epilogue-1 VALU + barrier)
    bf16x8 b2r[3][4];
#pragma unroll
    for (int p = 0; p < 3; ++p)
#pragma unroll
        for (int nt = 0; nt < 4; ++nt)
            b2r[p][nt] = *(const bf16x8*)(B2 +
                ((size_t)(((wv * 4 + nt) * 8 + p) * 64 + lane) << 3));

    // epilogue 1: h0 -> tH
    {
        float bv[4];
#pragma unroll
        for (int nt = 0; nt < 4; ++nt)
            bv[nt] = b0[e * HID + wv * 64 + nt * 16 + lr];
#pragma unroll
        for (int mt = 0; mt < 2; ++mt)
#pragma unroll
            for (int r = 0; r < 4; ++r) {
                const int row = mt * 16 + lq * 4 + r;
#pragma unroll
                for (int nt = 0; nt < 4; ++nt) {
                    const int n = wv * 64 + nt * 16 + lr;
                    float t = tanh_fast(acc[mt][nt][r] + bv[nt]);
                    tH[(n >> 5) * 1088 + row * 34 + (n & 31)] = (short)f2bf(t);
                }
            }
    }
    __syncthreads();

    // =============== Stage 2: z1 = h0 @ W1^T   (K=256, ring-3) =============
    ZERO_ACC();
#pragma unroll
    for (int ki = 0; ki < 8; ++ki) {
        bf16x8 af[2];
#pragma unroll
        for (int mt = 0; mt < 2; ++mt)
            af[mt] = *(const bf16x8*)&tH[ki * 1088 + (mt * 16 + lr) * 34 + lq * 8];
#pragma unroll
        for (int mt = 0; mt < 2; ++mt)
#pragma unroll
            for (int nt = 0; nt < 4; ++nt)
                acc[mt][nt] = __builtin_amdgcn_mfma_f32_16x16x32_bf16(
                    af[mt], b2r[ki % 3][nt], acc[mt][nt], 0, 0, 0);
        if (ki < 5) {
#pragma unroll
            for (int nt = 0; nt < 4; ++nt)
                b2r[ki % 3][nt] = *(const bf16x8*)(B2 +
                    ((size_t)(((wv * 4 + nt) * 8 + ki + 3) * 64 + lane) << 3));
        }
    }

    // S3 B-ring preload (hoisted above epilogue-2 + barrier)
    bf16x8 b3r[3][4];
#pragma unroll
    for (int p = 0; p < 3; ++p)
#pragma unroll
        for (int nt = 0; nt < 4; ++nt)
            b3r[p][nt] = *(const bf16x8*)(B3 +
                ((size_t)(((wv * 4 + nt) * 8 + p) * 64 + lane) << 3));

    // epilogue 2: dz1 -> tD; o partials -> red
    {
        float bv[4], w2v[4];
#pragma unroll
        for (int nt = 0; nt < 4; ++nt) {
            bv[nt]  = b1[e * HID + wv * 64 + nt * 16 + lr];
            w2v[nt] = W2[e * HID + wv * 64 + nt * 16 + lr];
        }
#pragma unroll
        for (int mt = 0; mt < 2; ++mt)
#pragma unroll
            for (int r = 0; r < 4; ++r) {
                const int row = mt * 16 + lq * 4 + r;
                float osum = 0.f;
#pragma unroll
                for (int nt = 0; nt < 4; ++nt) {
                    const int n = wv * 64 + nt * 16 + lr;
                    float t = tanh_fast(acc[mt][nt][r] + bv[nt]);
                    osum += t * w2v[nt];
                    tD[(n >> 5) * 1088 + row * 34 + (n & 31)] =
                        (short)f2bf(w2v[nt] * (1.f - t * t));
                }
                osum += __shfl_xor(osum, 1, 64);
                osum += __shfl_xor(osum, 2, 64);
                osum += __shfl_xor(osum, 4, 64);
                osum += __shfl_xor(osum, 8, 64);
                if (lr == 0) red[wv][row] = osum;
            }
    }
    __syncthreads();
    if (tid < 32) {
        int m = m0 + tid;
        if (m < cnt)
            o_atom[list[m]] = red[0][tid] + red[1][tid] + red[2][tid] +
                              red[3][tid] + b2[e];
    }

    // =============== Stage 3: dh0 = dz1 @ W1   (K=256, ring-3) =============
    ZERO_ACC();
#pragma unroll
    for (int ki = 0; ki < 8; ++ki) {
        bf16x8 af[2];
#pragma unroll
        for (int mt = 0; mt < 2; ++mt)
            af[mt] = *(const bf16x8*)&tD[ki * 1088 + (mt * 16 + lr) * 34 + lq * 8];
#pragma unroll
        for (int mt = 0; mt < 2; ++mt)
#pragma unroll
            for (int nt = 0; nt < 4; ++nt)
                acc[mt][nt] = __builtin_amdgcn_mfma_f32_16x16x32_bf16(
                    af[mt], b3r[ki % 3][nt], acc[mt][nt], 0, 0, 0);
        if (ki < 5) {
#pragma unroll
            for (int nt = 0; nt < 4; ++nt)
                b3r[ki % 3][nt] = *(const bf16x8*)(B3 +
                    ((size_t)(((wv * 4 + nt) * 8 + ki + 3) * 64 + lane) << 3));
        }
    }

    // S4 B-ring preload (hoisted above epilogue-3 + barrier)
    bf16x8 b4r[3][2];
#pragma unroll
    for (int p = 0; p < 3; ++p)
#pragma unroll
        for (int nt = 0; nt < 2; ++nt)
            b4r[p][nt] = *(const bf16x8*)(B4 +
                ((size_t)(((wv * 2 + nt) * 8 + p) * 64 + lane) << 3));

    // epilogue 3: dz0 = dh0*(1-h0^2) -> tH in-place (same thread owns slot)
#pragma unroll
    for (int mt = 0; mt < 2; ++mt)
#pragma unroll
        for (int r = 0; r < 4; ++r) {
            const int row = mt * 16 + lq * 4 + r;
#pragma unroll
            for (int nt = 0; nt < 4; ++nt) {
                const int n = wv * 64 + nt * 16 + lr;
                const int a = (n >> 5) * 1088 + row * 34 + (n & 31);
                float h = bf2f((unsigned short)tH[a]);
                tH[a] = (short)f2bf(acc[mt][nt][r] * (1.f - h * h));
            }
        }
    __syncthreads();

    // =============== Stage 4: g = dz0 @ W0   (K=256, NT=2, ring-3) =========
    {
        f32x4 a4[2][2];
#pragma unroll
        for (int mt = 0; mt < 2; ++mt)
#pragma unroll
            for (int nt = 0; nt < 2; ++nt)
#pragma unroll
                for (int j = 0; j < 4; ++j) a4[mt][nt][j] = 0.f;
#pragma unroll
        for (int ki = 0; ki < 8; ++ki) {
            bf16x8 af[2];
#pragma unroll
            for (int mt = 0; mt < 2; ++mt)
                af[mt] = *(const bf16x8*)&tH[ki * 1088 + (mt * 16 + lr) * 34 + lq * 8];
#pragma unroll
            for (int mt = 0; mt < 2; ++mt)
#pragma unroll
                for (int nt = 0; nt < 2; ++nt)
                    a4[mt][nt] = __builtin_amdgcn_mfma_f32_16x16x32_bf16(
                        af[mt], b4r[ki % 3][nt], a4[mt][nt], 0, 0, 0);
            if (ki < 5) {
#pragma unroll
                for (int nt = 0; nt < 2; ++nt)
                    b4r[ki % 3][nt] = *(const bf16x8*)(B4 +
                        ((size_t)(((wv * 2 + nt) * 8 + ki + 3) * 64 + lane) << 3));
            }
        }
        // epilogue 4: g -> tD chunk-major, then coalesced bf16x8 scatter
#pragma unroll
        for (int mt = 0; mt < 2; ++mt)
#pragma unroll
            for (int r = 0; r < 4; ++r) {
                const int row = mt * 16 + lq * 4 + r;
#pragma unroll
                for (int nt = 0; nt < 2; ++nt) {
                    const int n = wv * 32 + nt * 16 + lr;
                    tD[(n >> 5) * 1088 + row * 34 + (n & 31)] =
                        (short)f2bf(a4[mt][nt][r]);
                }
            }
    }
    __syncthreads();
#pragma unroll
    for (int t = 0; t < 2; ++t) {
        const int c = tid + 256 * t;         // 0..511
        const int row = c >> 4;              // 0..31
        const int pos = (c & 15) * 8;        // 0..120
        const int m = m0 + row;
        if (m < cnt) {
            bf16x8 v = *(const bf16x8*)&tD[(pos >> 5) * 1088 + row * 34 + (pos & 31)];
            *(bf16x8*)(Gb + (size_t)list[m] * IN_DIM + pos) = v;
        }
    }
#undef ZERO_ACC
}

// ---------------------------------------------------------------------------
// 3) Forces + energy fused (saves a dispatch). Forces part: 4 nnz/thread,
//    1954 blocks (transaction/latency bound ~110us floor at this structure).
//    Blocks < N_IMG additionally reduce their image's energy (img sorted ->
//    contiguous range, binary-searched; no atomics).
// ---------------------------------------------------------------------------
__global__ __launch_bounds__(256) void forces_kernel(
    const int* __restrict__ rows, const int* __restrict__ cols,
    const float* __restrict__ vals, const unsigned short* __restrict__ g,
    float* __restrict__ F,
    const float* __restrict__ o_atom, const int* __restrict__ img,
    float* __restrict__ energy) {
    const int i0 = (blockIdx.x * 256 + threadIdx.x) * 4;
    if (i0 < NNZ) {
        int4 r = *(const int4*)(rows + i0);
        int4 c = *(const int4*)(cols + i0);
        float4 v = *(const float4*)(vals + i0);
        float g0 = bf2f(g[r.x]), g1 = bf2f(g[r.y]);
        float g2 = bf2f(g[r.z]), g3 = bf2f(g[r.w]);
        atomicAdd(&F[c.x], -v.x * g0);
        atomicAdd(&F[c.y], -v.y * g1);
        atomicAdd(&F[c.z], -v.z * g2);
        atomicAdd(&F[c.w], -v.w * g3);
    }
    if (blockIdx.x < N_IMG) {
        const int b = blockIdx.x;
        int lo, hi;
        {
            int l = 0, r = N_ATOMS;
            while (l < r) { int m = (l + r) >> 1; if (img[m] < b) l = m + 1; else r = m; }
            lo = l;
        }
        {
            int l = lo, r = N_ATOMS;
            while (l < r) { int m = (l + r) >> 1; if (img[m] < b + 1) l = m + 1; else r = m; }
            hi = l;
        }
        float s = 0.f;
        for (int i = lo + (int)threadIdx.x; i < hi; i += 256) s += o_atom[i];
#pragma unroll
        for (int off = 32; off > 0; off >>= 1) s += __shfl_down(s, off, 64);
        __shared__ float red[4];
        if ((threadIdx.x & 63) == 0) red[threadIdx.x >> 6] = s;
        __syncthreads();
        if (threadIdx.x == 0) energy[b] = red[0] + red[1] + red[2] + red[3];
    }
}

// ---------------------------------------------------------------------------
extern "C" void kernel_launch(void* const* d_in, const int* in_sizes, int n_in,
                              void* d_out, int out_size, void* d_ws, size_t ws_size,
                              hipStream_t stream) {
    const float* fp    = (const float*)d_in[0];
    const int*   Z     = (const int*)d_in[1];
    const int*   img   = (const int*)d_in[2];
    const int*   frows = (const int*)d_in[3];
    const int*   fcols = (const int*)d_in[4];
    const float* fvals = (const float*)d_in[5];
    const float* W0    = (const float*)d_in[6];
    const float* b0    = (const float*)d_in[7];
    const float* W1    = (const float*)d_in[8];
    const float* b1    = (const float*)d_in[9];
    const float* W2    = (const float*)d_in[10];
    const float* b2    = (const float*)d_in[11];

    float* out    = (float*)d_out;
    float* energy = out;             // [N_IMG]
    float* F      = out + N_IMG;     // [3*N_ATOMS]

    char* ws = (char*)d_ws;
    int*   counts = (int*)ws;                                   // 16 B
    int*   lists  = (int*)(ws + 1024);                          // 800 KB
    char*  base   = ws + (1 << 20);
    unsigned short* Gb   = (unsigned short*)(base);              // 50000*128 bf16 (atom order)
    float* o_atom        = (float*)(base + 13000000);            // 50000 f32
    unsigned short* W0s1 = (unsigned short*)(base + 14000000);   // swizzled, 256 KB
    unsigned short* W0s4 = W0s1 + N_ELEM * IN_DIM * HID;         // swizzled, 256 KB
    unsigned short* W1s2 = W0s4 + N_ELEM * IN_DIM * HID;         // swizzled, 512 KB
    unsigned short* W1s3 = W1s2 + N_ELEM * HID * HID;            // swizzled, 512 KB

    // 4 dispatches: prep(+counts0), bucket(+F0), fused, forces(+energy)
    prep_weights<<<(N_ELEM * HID * HID + 255) / 256, 256, 0, stream>>>(
        W0, W1, W0s1, W1s2, W1s3, W0s4, counts);
    bucket_kernel<<<(N_ATOMS + 255) / 256, 256, 0, stream>>>(Z, counts, lists, F);

    const int MT = (N_ATOMS + 31) / 32;   // 1563 x-tiles; ~391/element active
    fused_mlp<<<dim3(MT, 1, N_ELEM), 256, 0, stream>>>(
        fp, W0s1, W1s2, W1s3, W0s4, b0, b1, W2, b2, o_atom, Gb, counts, lists);

    forces_kernel<<<(NNZ / 4 + 255) / 256, 256, 0, stream>>>(
        frows, fcols, fvals, Gb, F, o_atom, img, energy);
}